// Round 4
// baseline (583.159 us; speedup 1.0000x reference)
//
#include <hip/hip_runtime.h>
#include <hip/hip_bf16.h>

// B=1, N=128, C=128, H=8, D=16. SCALE=0.25. All I/O fp32.
// GEMMs: bf16 MFMA, split-bf16 hi/lo 3-term for fp32 quality.
// Attention planes are HI-ONLY bf16. Plane arrays: [plane][dhalf][p][8] ushort.
// v10: persistent mega-kernel, REGULAR launch (cooperative launch is dropped
// under graph capture -> v9 produced zeros). Grid barrier = device-global
// generation counter + agent-scope fences (what cg::sync does internally),
// bounded spin (no-hang). 512 blocks x 256 thr = exactly 2 blocks/CU.
// P2 attn: plane-grouped (4 j per block), E/G cached in VGPRs across j.
// P3 gemm_out: 64x64 tiles, all 512 blocks.

#define NPOS 16384
#define CDIM 128
#define NBLK 512

typedef __attribute__((ext_vector_type(8))) short bf16x8;
typedef __attribute__((ext_vector_type(8))) unsigned short u16x8;
typedef __attribute__((ext_vector_type(4))) float f32x4;

#define MFMA16(a, b, c) __builtin_amdgcn_mfma_f32_16x16x32_bf16((a), (b), (c), 0, 0, 0)

#define GLL16(gp, lp) __builtin_amdgcn_global_load_lds( \
    (const __attribute__((address_space(1))) void*)(gp), \
    (__attribute__((address_space(3))) void*)(lp), 16, 0, 0)

static __device__ __forceinline__ unsigned short f2bf(float x) {
    union { float f; unsigned int u; } v; v.f = x;
    unsigned int u = v.u;
    unsigned int r = u + 0x7FFFu + ((u >> 16) & 1u);   // RNE
    return (unsigned short)(r >> 16);
}
static __device__ __forceinline__ float bf2f(unsigned short h) {
    union { float f; unsigned int u; } v; v.u = ((unsigned int)h) << 16; return v.f;
}

// ---- software grid barrier (module .data: NOT poisoned by harness fills) ----
__device__ unsigned g_cnt = 0;
__device__ unsigned g_gen = 0;

static __device__ __forceinline__ void gbar() {
    __syncthreads();
    __threadfence();   // release: agent-scope, flushes L1/L2 writes cross-XCD
    if (threadIdx.x == 0) {
        unsigned my = __hip_atomic_load(&g_gen, __ATOMIC_RELAXED,
                                        __HIP_MEMORY_SCOPE_AGENT);
        unsigned arrived = __hip_atomic_fetch_add(&g_cnt, 1u, __ATOMIC_ACQ_REL,
                                                  __HIP_MEMORY_SCOPE_AGENT) + 1u;
        if (arrived == NBLK) {
            __hip_atomic_store(&g_cnt, 0u, __ATOMIC_RELAXED,
                               __HIP_MEMORY_SCOPE_AGENT);
            __hip_atomic_store(&g_gen, my + 1u, __ATOMIC_RELEASE,
                               __HIP_MEMORY_SCOPE_AGENT);
        } else {
            int spins = 0;
            while (__hip_atomic_load(&g_gen, __ATOMIC_ACQUIRE,
                                     __HIP_MEMORY_SCOPE_AGENT) == my) {
                __builtin_amdgcn_s_sleep(8);
                if (++spins > (1 << 17)) break;   // bounded: fail, don't hang
            }
        }
    }
    __threadfence();   // acquire side: invalidate stale lines
    __syncthreads();
}

struct KParams {
    const float *e, *mask, *lnw, *lnb;
    const float *wq1, *we1, *wq2, *we2, *wo;
    const float *bq_i, *be_i, *bq_o, *be_o, *b_o;
    unsigned short *e_hl, *B1t, *B2t, *B3t;
    unsigned short *QT, *KT, *VT, *Etab, *Gtab;
    float *va, *out;
};

__global__ __launch_bounds__(256, 2) void fused_kernel(KParams P)
{
    __shared__ __align__(16) unsigned char smem[39424];

    const int t = threadIdx.x;
    const int bid = blockIdx.x;
    const int wave = t >> 6, lane = t & 63;
    const int m = lane & 15, q = lane >> 4;

    // ================= P0: prep (LN + weight packs) =================
    for (int vb = bid; vb < 4672; vb += NBLK) {
        if (vb < 4096) {
            const int row = vb * 4 + (t >> 6);
            float2 x = *(const float2*)(P.e + (size_t)row * CDIM + lane * 2);
            float s = x.x + x.y, s2 = x.x * x.x + x.y * x.y;
            #pragma unroll
            for (int off = 1; off < 64; off <<= 1) {
                s  += __shfl_xor(s,  off, 64);
                s2 += __shfl_xor(s2, off, 64);
            }
            float mm = s * (1.f / 128.f);
            float vv = s2 * (1.f / 128.f) - mm * mm;
            float sc = rsqrtf(vv + 1e-5f);
            float2 wv = *(const float2*)(P.lnw + lane * 2);
            float2 bv = *(const float2*)(P.lnb + lane * 2);
            float y0 = (x.x - mm) * sc * wv.x + bv.x;
            float y1 = (x.y - mm) * sc * wv.y + bv.y;
            unsigned short h0 = f2bf(y0), h1 = f2bf(y1);
            ushort2 hi = {h0, h1};
            ushort2 lo = {f2bf(y0 - bf2f(h0)), f2bf(y1 - bf2f(h1))};
            *(ushort2*)(P.e_hl + (size_t)row * 256 + lane * 2)       = hi;
            *(ushort2*)(P.e_hl + (size_t)row * 256 + 128 + lane * 2) = lo;
        } else if (vb < 4544) {
            int pb = vb - 4096;
            const float* wq; const float* we; unsigned short* Bt;
            if (pb < 224) { wq = P.wq1; we = P.we1; Bt = P.B1t; }
            else          { pb -= 224; wq = P.wq2; we = P.we2; Bt = P.B2t; }
            const int idx = pb * 256 + t;    // n*128 + k
            const int n = idx >> 7, k = idx & 127;
            float v = 0.f;
            if (n < 384) v = wq[(size_t)k * 384 + n];
            else if (n < 400) v = we[(size_t)k * 16 + (n - 384)];
            unsigned short hi = f2bf(v);
            Bt[idx] = hi;
            Bt[448 * 128 + idx] = f2bf(v - bf2f(hi));
        } else {
            const int idx = (vb - 4544) * 256 + t;   // n*256 + kp
            const int n = idx >> 8, kp = idx & 255;
            const int d = kp & 15, pl = kp >> 4;
            const int k = d * 16 + pl;
            float v = P.wo[(size_t)k * 128 + n];
            unsigned short hi = f2bf(v);
            P.B3t[idx] = hi;
            P.B3t[128 * 256 + idx] = f2bf(v - bf2f(hi));
        }
    }
    gbar();

    // ================= P1: gemm_qkv (+transpose +tables) =================
    // vb = (br*7 + by)*128 + c. Tile 128(M) x 64(N), K=128 in 4 chunks.
    for (int vb = bid; vb < 1792; vb += NBLK) {
        unsigned short* Alds = (unsigned short*)smem;            // [2][4][128][8]
        unsigned short* Blds = (unsigned short*)(smem + 16384);  // [2][4][64][8]
        const int craw = vb & 127;
        const int rem = vb >> 7;          // 0..13
        const int by = rem % 7;
        const int br = rem / 7;
        const int bx = ((craw & 31) << 2) | (craw >> 5);  // bx quads share an XCD
        const int W0blk = bx * 128;
        const int N0 = by * 64;
        const unsigned short* Bt = br ? P.B2t : P.B1t;
        const float* bias_qkv = br ? P.bq_o : P.bq_i;
        const float* bias_eg  = br ? P.be_o : P.be_i;

        f32x4 acc[2][4];
        #pragma unroll
        for (int a = 0; a < 2; ++a)
            #pragma unroll
            for (int cc = 0; cc < 4; ++cc) acc[a][cc] = (f32x4){0.f, 0.f, 0.f, 0.f};

        for (int kc = 0; kc < 4; ++kc) {
            #pragma unroll
            for (int ii = 0; ii < 6; ++ii) {
                const int id = wave + ii * 4;
                if (id < 16) {
                    const int hl = id >> 3, s = id & 7;
                    const int qq = s >> 1, rbase = (s & 1) * 64;
                    const unsigned short* g = P.e_hl
                        + (size_t)(W0blk + rbase + lane) * 256 + hl * 128 + kc * 32 + qq * 8;
                    unsigned short* l = Alds + hl * 4096 + qq * 1024 + rbase * 8;
                    GLL16(g, l);
                } else {
                    const int id2 = id - 16;
                    const int hl = id2 >> 2, qq = id2 & 3;
                    const unsigned short* g = Bt + (size_t)(N0 + lane) * 128
                        + hl * (448 * 128) + kc * 32 + qq * 8;
                    unsigned short* l = Blds + hl * 2048 + qq * 512;
                    GLL16(g, l);
                }
            }
            __syncthreads();   // drains vmcnt: staged data visible

            bf16x8 aH[2], aL[2], bH[4], bL[4];
            #pragma unroll
            for (int ms = 0; ms < 2; ++ms) {
                const int row = wave * 32 + ms * 16 + m;
                aH[ms] = *(const bf16x8*)(Alds + 0    + q * 1024 + row * 8);
                aL[ms] = *(const bf16x8*)(Alds + 4096 + q * 1024 + row * 8);
            }
            #pragma unroll
            for (int ns = 0; ns < 4; ++ns) {
                bH[ns] = *(const bf16x8*)(Blds + 0    + q * 512 + (ns * 16 + m) * 8);
                bL[ns] = *(const bf16x8*)(Blds + 2048 + q * 512 + (ns * 16 + m) * 8);
            }
            #pragma unroll
            for (int ns = 0; ns < 4; ++ns) {
                acc[0][ns] = MFMA16(aH[0], bH[ns], acc[0][ns]);
                acc[1][ns] = MFMA16(aH[1], bH[ns], acc[1][ns]);
            }
            #pragma unroll
            for (int ns = 0; ns < 4; ++ns) {
                acc[0][ns] = MFMA16(aL[0], bH[ns], acc[0][ns]);
                acc[1][ns] = MFMA16(aL[1], bH[ns], acc[1][ns]);
            }
            #pragma unroll
            for (int ns = 0; ns < 4; ++ns) {
                acc[0][ns] = MFMA16(aH[0], bL[ns], acc[0][ns]);
                acc[1][ns] = MFMA16(aH[1], bL[ns], acc[1][ns]);
            }
            __syncthreads();   // LDS reusable (next chunk / epilogue)
        }

        if (by < 6) {
            unsigned short (*Ts16)[66] = (unsigned short (*)[66])smem;
            #pragma unroll
            for (int ms = 0; ms < 2; ++ms)
                #pragma unroll
                for (int ns = 0; ns < 4; ++ns) {
                    const int lc = ns * 16 + m;
                    const int col = N0 + lc;
                    const float bias = bias_qkv[col];
                    const float scale = (col < 128) ? 0.25f : 1.f;
                    #pragma unroll
                    for (int r = 0; r < 4; ++r) {
                        const int lr = wave * 32 + ms * 16 + q * 4 + r;
                        Ts16[lr][lc] = f2bf((acc[ms][ns][r] + bias) * scale);
                    }
                }
            __syncthreads();
            const int qsel = by >> 1, dhalf = by & 1;
            unsigned short* dstH = (qsel == 0) ? P.QT : (qsel == 1 ? P.KT : P.VT);
            // j-major (transposed) for subplanes attn reads column-wise:
            const bool tr = (qsel == 0) || (br == 1);
            #pragma unroll
            for (int it = 0; it < 4; ++it) {
                int item = it * 256 + t;        // 0..1023: (hh, lr)
                int hh = item >> 7, lr = item & 127;
                u16x8 hi;
                #pragma unroll
                for (int dd = 0; dd < 8; ++dd)
                    hi[dd] = Ts16[lr][dd * 8 + hh];
                const size_t sub = ((size_t)(br * 8 + hh) * 2 + dhalf) * NPOS;
                const size_t p16 = tr ? ((size_t)lr * 128 + bx)
                                      : ((size_t)bx * 128 + lr);
                *(u16x8*)(dstH + (sub + p16) * 8) = hi;
            }
        } else {
            float* Tf = (float*)smem;   // [128][33], cols 0..15 used
            #pragma unroll
            for (int ms = 0; ms < 2; ++ms) {
                const float bias = bias_eg[m];
                #pragma unroll
                for (int r = 0; r < 4; ++r) {
                    const int lr = wave * 32 + ms * 16 + q * 4 + r;
                    Tf[lr * 33 + m] = acc[ms][0][r] + bias;
                }
            }
            __syncthreads();
            // Row p = bx*128 + r128. br=0: dst = p; br=1: dst = r128*128 + bx.
            const int r128 = t & 127, grp = t >> 7;
            const float mk = P.mask[bx * 128 + r128];
            const int dst = br ? (r128 * 128 + bx) : (bx * 128 + r128);
            if (grp == 0) {
                #pragma unroll
                for (int h = 0; h < 8; ++h)
                    P.Etab[(size_t)(br * 8 + h) * NPOS + dst] =
                        f2bf(Tf[r128 * 33 + h] + mk);
            } else {
                #pragma unroll
                for (int h = 0; h < 8; ++h) {
                    const float g = Tf[r128 * 33 + 8 + h] + mk;
                    P.Gtab[(size_t)(br * 8 + h) * NPOS + dst] =
                        f2bf(1.f / (1.f + __expf(-g)));
                }
            }
        }
        __syncthreads();   // LDS reuse across vb iterations
    }
    gbar();

    // ================= P2: attn (plane-grouped, E/G cached in VGPRs) =======
    // block owns plane = bid>>5, j = (bid&31)*4 + it (4 iterations).
    {
        const int plane = bid >> 5;            // 0..15
        const int j0 = (bid & 31) * 4;
        unsigned short* Vth = (unsigned short*)smem;            // [16*136]
        unsigned short* Pl  = (unsigned short*)(smem + 4352);   // [128*136]
        const size_t SP = (size_t)NPOS * 8;
        const unsigned short* __restrict__ Eb = P.Etab + (size_t)plane * NPOS;
        const unsigned short* __restrict__ Gb = P.Gtab + (size_t)plane * NPOS;
        const int strip = wave * 32;

        // E/G register cache (j-independent): 64 VGPR
        u16x8 Ec[2][4], Gc[2][4];
        #pragma unroll
        for (int mt = 0; mt < 2; ++mt)
            #pragma unroll
            for (int r = 0; r < 4; ++r) {
                const int i = strip + mt * 16 + q * 4 + r;
                Ec[mt][r] = *(const u16x8*)(Eb + (size_t)i * 128 + m * 8);
                Gc[mt][r] = *(const u16x8*)(Gb + (size_t)i * 128 + m * 8);
            }

        for (int it = 0; it < 4; ++it) {
            const int j = j0 + it;
            const size_t jb = (size_t)j * 128 * 8;

            f32x4 S[2][8];
            #pragma unroll
            for (int mt = 0; mt < 2; ++mt)
                #pragma unroll
                for (int r = 0; r < 4; ++r) {
                    #pragma unroll
                    for (int nt = 0; nt < 8; ++nt)
                        S[mt][nt][r] = bf2f(Ec[mt][r][nt]);
                }

            {   // stage V transposed+permuted: Vth[d*136 + c] = V[k(c)][d]
                int c = t >> 1, ch = t & 1;
                int krow = (c & 15) * 8 + (c >> 4);
                const unsigned short* src = P.VT + (size_t)(plane * 2 + ch) * SP
                                          + jb + (size_t)krow * 8;
                u16x8 v = *(const u16x8*)src;
                #pragma unroll
                for (int dd = 0; dd < 8; ++dd)
                    Vth[(ch * 8 + dd) * 136 + c] = v[dd];
            }

            const bf16x8 zero8 = {};
            const int hf = q & 1;
            const size_t qko = (size_t)(plane * 2 + hf) * SP + jb;

            bf16x8 aQ[2];
            #pragma unroll
            for (int mt = 0; mt < 2; ++mt) {
                const size_t off = qko + (size_t)(strip + mt * 16 + m) * 8;
                aQ[mt] = (q < 2) ? *(const bf16x8*)(P.QT + off) : zero8;
            }

            #pragma unroll
            for (int nt = 0; nt < 8; ++nt) {
                const size_t koff = qko + (size_t)(m * 8 + nt) * 8;
                bf16x8 bK = (q < 2) ? *(const bf16x8*)(P.KT + koff) : zero8;
                #pragma unroll
                for (int mt = 0; mt < 2; ++mt)
                    S[mt][nt] = MFMA16(aQ[mt], bK, S[mt][nt]);
            }

            #pragma unroll
            for (int mt = 0; mt < 2; ++mt)
                #pragma unroll
                for (int r = 0; r < 4; ++r) {
                    float v = -1e30f;
                    #pragma unroll
                    for (int nt = 0; nt < 8; ++nt) v = fmaxf(v, S[mt][nt][r]);
                    v = fmaxf(v, __shfl_xor(v, 1)); v = fmaxf(v, __shfl_xor(v, 2));
                    v = fmaxf(v, __shfl_xor(v, 4)); v = fmaxf(v, __shfl_xor(v, 8));
                    float s = 0.f;
                    #pragma unroll
                    for (int nt = 0; nt < 8; ++nt) {
                        float p = __expf(S[mt][nt][r] - v);
                        S[mt][nt][r] = p;
                        s += p;
                    }
                    s += __shfl_xor(s, 1); s += __shfl_xor(s, 2);
                    s += __shfl_xor(s, 4); s += __shfl_xor(s, 8);
                    const float inv = 1.f / s;
                    const int i = strip + mt * 16 + q * 4 + r;
                    #pragma unroll
                    for (int nt = 0; nt < 4; ++nt) {
                        Pl[i * 136 + nt * 16 + m] =
                            f2bf(S[mt][nt][r] * inv * bf2f(Gc[mt][r][nt]));
                        Pl[i * 136 + (nt + 4) * 16 + m] =
                            f2bf(S[mt][nt + 4][r] * inv * bf2f(Gc[mt][r][nt + 4]));
                    }
                }

            __syncthreads();   // Vth/Pl ready

            f32x4 av[2] = {(f32x4){0.f, 0.f, 0.f, 0.f}, (f32x4){0.f, 0.f, 0.f, 0.f}};
            #pragma unroll
            for (int kc = 0; kc < 4; ++kc) {
                const int off = kc * 32 + q * 8;
                bf16x8 bV = *(const bf16x8*)&Vth[m * 136 + off];
                #pragma unroll
                for (int mt = 0; mt < 2; ++mt) {
                    bf16x8 aP = *(const bf16x8*)&Pl[(strip + mt * 16 + m) * 136 + off];
                    av[mt] = MFMA16(aP, bV, av[mt]);
                }
            }

            #pragma unroll
            for (int mt = 0; mt < 2; ++mt)
                #pragma unroll
                for (int r = 0; r < 4; ++r) {
                    const int i = strip + mt * 16 + q * 4 + r;
                    P.va[((size_t)(j * 128 + i)) * 256 + plane * 16 + m] = av[mt][r];
                }
            __syncthreads();   // LDS reuse across j iterations
        }
    }
    gbar();

    // ================= P3: gemm_out =================
    // 512 blocks: px = bid>>1 (row tile), ny = bid&1 (col half). 64x64, K=256.
    {
        const int W0 = (bid >> 1) * 64 + wave * 16;
        const int N0 = (bid & 1) * 64;

        f32x4 acc[4];
        #pragma unroll
        for (int cc = 0; cc < 4; ++cc) acc[cc] = (f32x4){0.f, 0.f, 0.f, 0.f};

        const float* arow = P.va + (size_t)(W0 + m) * 256;
        const unsigned short* bcol[4];
        #pragma unroll
        for (int ns = 0; ns < 4; ++ns)
            bcol[ns] = P.B3t + (size_t)(N0 + ns * 16 + m) * 256;

        #pragma unroll 2
        for (int kc = 0; kc < 8; ++kc) {
            const int ko = kc * 32 + q * 8;
            const float4* ap = (const float4*)(arow + ko);
            float4 f0 = ap[0], f1 = ap[1];
            float xs[8] = {f0.x, f0.y, f0.z, f0.w, f1.x, f1.y, f1.z, f1.w};
            bf16x8 ah, al;
            #pragma unroll
            for (int jj = 0; jj < 8; ++jj) {
                unsigned short hh = f2bf(xs[jj]);
                ah[jj] = (short)hh;
                al[jj] = (short)f2bf(xs[jj] - bf2f(hh));
            }
            bf16x8 bh[4], bl[4];
            #pragma unroll
            for (int ns = 0; ns < 4; ++ns) {
                bh[ns] = *(const bf16x8*)(bcol[ns] + ko);
                bl[ns] = *(const bf16x8*)(bcol[ns] + 128 * 256 + ko);
            }
            #pragma unroll
            for (int ns = 0; ns < 4; ++ns) acc[ns] = MFMA16(ah, bh[ns], acc[ns]);
            #pragma unroll
            for (int ns = 0; ns < 4; ++ns) acc[ns] = MFMA16(al, bh[ns], acc[ns]);
            #pragma unroll
            for (int ns = 0; ns < 4; ++ns) acc[ns] = MFMA16(ah, bl[ns], acc[ns]);
        }

        #pragma unroll
        for (int ns = 0; ns < 4; ++ns) {
            const int col = N0 + ns * 16 + m;
            #pragma unroll
            for (int r = 0; r < 4; ++r) {
                const int prow = W0 + q * 4 + r;                 // p' = j*128+i
                const int orow = ((prow & 127) << 7) | (prow >> 7);  // i*128+j
                P.out[(size_t)orow * 128 + col] = acc[ns][r] + P.b_o[col];
            }
        }
    }
}

extern "C" void kernel_launch(void* const* d_in, const int* in_sizes, int n_in,
                              void* d_out, int out_size, void* d_ws, size_t ws_size,
                              hipStream_t stream) {
    char* base = (char*)d_ws;
    const size_t PLANE = (size_t)16 * NPOS * 16;                      // ushorts per array
    unsigned short* e_hl = (unsigned short*)base;                     // 8.39 MB
    unsigned short* QT = (unsigned short*)(base + (size_t)NPOS * 256 * 2);
    unsigned short* KT = QT + PLANE;
    unsigned short* VT = KT + PLANE;
    float* va = (float*)(VT + PLANE);                                 // 16.78 MB
    unsigned short* Etab = (unsigned short*)(va + (size_t)NPOS * 256);// 0.52 MB (bf16)
    unsigned short* Gtab = Etab + (size_t)16 * NPOS;                  // 0.52 MB
    unsigned short* B3t  = Gtab + (size_t)16 * NPOS;                  // 0.13 MB

    // aliases (lifetime-checked): B1t/B2t overlay va; P0 writes them, P1 reads
    // them, va is first written in P2 — all separated by grid barriers.
    unsigned short* B1t = (unsigned short*)va;
    unsigned short* B2t = B1t + (size_t)2 * 448 * 128;

    KParams Pr;
    Pr.e    = (const float*)d_in[0];
    Pr.mask = (const float*)d_in[1];
    Pr.lnw  = (const float*)d_in[2];
    Pr.lnb  = (const float*)d_in[3];
    Pr.wq1  = (const float*)d_in[4];
    Pr.bq_i = (const float*)d_in[5];
    Pr.we1  = (const float*)d_in[6];
    Pr.be_i = (const float*)d_in[7];
    Pr.wq2  = (const float*)d_in[8];
    Pr.bq_o = (const float*)d_in[9];
    Pr.we2  = (const float*)d_in[10];
    Pr.be_o = (const float*)d_in[11];
    Pr.wo   = (const float*)d_in[12];
    Pr.b_o  = (const float*)d_in[13];
    Pr.e_hl = e_hl; Pr.B1t = B1t; Pr.B2t = B2t; Pr.B3t = B3t;
    Pr.QT = QT; Pr.KT = KT; Pr.VT = VT; Pr.Etab = Etab; Pr.Gtab = Gtab;
    Pr.va = va; Pr.out = (float*)d_out;

    fused_kernel<<<NBLK, 256, 0, stream>>>(Pr);
}

// Round 5
// 185.703 us; speedup vs baseline: 3.1403x; 3.1403x over previous
//
#include <hip/hip_runtime.h>
#include <hip/hip_bf16.h>

// B=1, N=128, C=128, H=8, D=16. SCALE=0.25. All I/O fp32.
// GEMMs: bf16 MFMA, split-bf16 hi/lo 3-term for fp32 quality.
// Attention planes are HI-ONLY bf16. Plane arrays: [plane][dhalf][p][8] ushort.
// v11 = v8 (4 kernels; mega-kernel refuted in r4: software grid barrier's
// per-WG L2 flush costs >> kernel boundaries) + three bit-identical tweaks:
//  - va stored as bf16 hi/lo by attn; gemm_out reads it directly (half the
//    bytes, no convert chain in gemm_out's K loop).
//  - gemm_out: 512 blocks of 64x64 (2 blocks/CU).
//  - attn: 1024 blocks x 2 j each, E/G cached in VGPRs across the pair.

#define NPOS 16384
#define CDIM 128

typedef __attribute__((ext_vector_type(8))) short bf16x8;
typedef __attribute__((ext_vector_type(8))) unsigned short u16x8;
typedef __attribute__((ext_vector_type(4))) float f32x4;

#define MFMA16(a, b, c) __builtin_amdgcn_mfma_f32_16x16x32_bf16((a), (b), (c), 0, 0, 0)

#define GLL16(gp, lp) __builtin_amdgcn_global_load_lds( \
    (const __attribute__((address_space(1))) void*)(gp), \
    (__attribute__((address_space(3))) void*)(lp), 16, 0, 0)

static __device__ __forceinline__ unsigned short f2bf(float x) {
    union { float f; unsigned int u; } v; v.f = x;
    unsigned int u = v.u;
    unsigned int r = u + 0x7FFFu + ((u >> 16) & 1u);   // RNE
    return (unsigned short)(r >> 16);
}
static __device__ __forceinline__ float bf2f(unsigned short h) {
    union { float f; unsigned int u; } v; v.u = ((unsigned int)h) << 16; return v.f;
}

// ---------------- prep: LayerNorm + all 3 weight packs, one kernel ---------
// blocks 0..4095: ln (4 rows each); 4096..4319: pack B1t; 4320..4543: pack
// B2t; 4544..4671: pack B3t (w_o, k' = (br*8+h)*16+d ordering).
__global__ __launch_bounds__(256) void prep_kernel(
    const float* __restrict__ e, const float* __restrict__ lnw,
    const float* __restrict__ lnb, unsigned short* __restrict__ e_hl,
    const float* __restrict__ wq1, const float* __restrict__ we1,
    unsigned short* __restrict__ B1t,
    const float* __restrict__ wq2, const float* __restrict__ we2,
    unsigned short* __restrict__ B2t,
    const float* __restrict__ wo, unsigned short* __restrict__ B3t)
{
    const int t = threadIdx.x;
    const int bx = blockIdx.x;
    if (bx < 4096) {
        const int lane = t & 63;
        const int row = bx * 4 + (t >> 6);
        float2 x = *(const float2*)(e + (size_t)row * CDIM + lane * 2);
        float s = x.x + x.y, s2 = x.x * x.x + x.y * x.y;
        #pragma unroll
        for (int off = 1; off < 64; off <<= 1) {
            s  += __shfl_xor(s,  off, 64);
            s2 += __shfl_xor(s2, off, 64);
        }
        float m = s * (1.f / 128.f);
        float v = s2 * (1.f / 128.f) - m * m;
        float sc = rsqrtf(v + 1e-5f);
        float2 wv = *(const float2*)(lnw + lane * 2);
        float2 bv = *(const float2*)(lnb + lane * 2);
        float y0 = (x.x - m) * sc * wv.x + bv.x;
        float y1 = (x.y - m) * sc * wv.y + bv.y;
        unsigned short h0 = f2bf(y0), h1 = f2bf(y1);
        ushort2 hi = {h0, h1};
        ushort2 lo = {f2bf(y0 - bf2f(h0)), f2bf(y1 - bf2f(h1))};
        *(ushort2*)(e_hl + (size_t)row * 256 + lane * 2)       = hi;
        *(ushort2*)(e_hl + (size_t)row * 256 + 128 + lane * 2) = lo;
    } else if (bx < 4544) {
        int pb = bx - 4096;
        const float* wq; const float* we; unsigned short* Bt;
        if (pb < 224) { wq = wq1; we = we1; Bt = B1t; }
        else          { pb -= 224; wq = wq2; we = we2; Bt = B2t; }
        const int idx = pb * 256 + t;    // n*128 + k
        const int n = idx >> 7, k = idx & 127;
        float v = 0.f;
        if (n < 384) v = wq[(size_t)k * 384 + n];
        else if (n < 400) v = we[(size_t)k * 16 + (n - 384)];
        unsigned short hi = f2bf(v);
        Bt[idx] = hi;
        Bt[448 * 128 + idx] = f2bf(v - bf2f(hi));
    } else {
        const int idx = (bx - 4544) * 256 + t;   // n*256 + kp
        const int n = idx >> 8, kp = idx & 255;
        const int d = kp & 15, pl = kp >> 4;
        const int k = d * 16 + pl;
        float v = wo[(size_t)k * 128 + n];
        unsigned short hi = f2bf(v);
        B3t[idx] = hi;
        B3t[128 * 256 + idx] = f2bf(v - bf2f(hi));
    }
}

// ---------------- MFMA GEMM: qkv+eg, global_load_lds staging, fused store --
// grid(128, 7, 2), 256 thr. Tile 128(M) x 64(N). K=128 in 4 chunks.
// LDS: A [hl][q][128 row][16B] 16KB, B [hl][q][64 col][16B] 8KB (aliased by
// the epilogue Ts tile). by 0,1: Q d-halves; 2,3: K; 4,5: V; 6: eg -> tables.
// Subplanes consumed column-wise by attn (Q all br, K/V br=1) are stored
// j-major directly; bx is XCD-chunk swizzled so the 4 blocks sharing a 64B
// output line sit on one XCD's L2.
__global__ __launch_bounds__(256) void gemm_qkv_kernel(
    const unsigned short* __restrict__ e_hl,
    const unsigned short* __restrict__ B1t, const unsigned short* __restrict__ B2t,
    const float* __restrict__ bq_i, const float* __restrict__ be_i,
    const float* __restrict__ bq_o, const float* __restrict__ be_o,
    const float* __restrict__ mask,
    unsigned short* __restrict__ QT, unsigned short* __restrict__ KT,
    unsigned short* __restrict__ VT,
    unsigned short* __restrict__ Etab, unsigned short* __restrict__ Gtab)
{
    __shared__ __align__(16) unsigned char smem[24576];
    unsigned short* Alds = (unsigned short*)smem;            // [2][4][128][8] ushorts
    unsigned short* Blds = (unsigned short*)(smem + 16384);  // [2][4][64][8]

    const int t = threadIdx.x;
    const int wave = t >> 6, lane = t & 63;
    const int m = lane & 15, q = lane >> 4;
    const int c = blockIdx.x;
    const int bx = ((c & 31) << 2) | (c >> 5);   // bx quads share an XCD
    const int W0blk = bx * 128;
    const int by = blockIdx.y;
    const int N0 = by * 64;
    const int br = blockIdx.z;
    const unsigned short* Bt = br ? B2t : B1t;
    const float* bias_qkv = br ? bq_o : bq_i;
    const float* bias_eg  = br ? be_o : be_i;

    f32x4 acc[2][4];
    #pragma unroll
    for (int a = 0; a < 2; ++a)
        #pragma unroll
        for (int cc = 0; cc < 4; ++cc) acc[a][cc] = (f32x4){0.f, 0.f, 0.f, 0.f};

    for (int kc = 0; kc < 4; ++kc) {
        // ---- stage A+B chunk into LDS: 24 wave-instrs, 6 per wave ----
        #pragma unroll
        for (int ii = 0; ii < 6; ++ii) {
            const int id = wave + ii * 4;
            if (id < 16) {
                const int hl = id >> 3, s = id & 7;
                const int qq = s >> 1, rbase = (s & 1) * 64;
                const unsigned short* g = e_hl
                    + (size_t)(W0blk + rbase + lane) * 256 + hl * 128 + kc * 32 + qq * 8;
                unsigned short* l = Alds + hl * 4096 + qq * 1024 + rbase * 8;
                GLL16(g, l);
            } else {
                const int id2 = id - 16;
                const int hl = id2 >> 2, qq = id2 & 3;
                const unsigned short* g = Bt + (size_t)(N0 + lane) * 128
                    + hl * (448 * 128) + kc * 32 + qq * 8;
                unsigned short* l = Blds + hl * 2048 + qq * 512;
                GLL16(g, l);
            }
        }
        __syncthreads();   // drains vmcnt: staged data visible

        bf16x8 aH[2], aL[2], bH[4], bL[4];
        #pragma unroll
        for (int ms = 0; ms < 2; ++ms) {
            const int row = wave * 32 + ms * 16 + m;
            aH[ms] = *(const bf16x8*)(Alds + 0    + q * 1024 + row * 8);
            aL[ms] = *(const bf16x8*)(Alds + 4096 + q * 1024 + row * 8);
        }
        #pragma unroll
        for (int ns = 0; ns < 4; ++ns) {
            bH[ns] = *(const bf16x8*)(Blds + 0    + q * 512 + (ns * 16 + m) * 8);
            bL[ns] = *(const bf16x8*)(Blds + 2048 + q * 512 + (ns * 16 + m) * 8);
        }
        #pragma unroll
        for (int ns = 0; ns < 4; ++ns) {
            acc[0][ns] = MFMA16(aH[0], bH[ns], acc[0][ns]);
            acc[1][ns] = MFMA16(aH[1], bH[ns], acc[1][ns]);
        }
        #pragma unroll
        for (int ns = 0; ns < 4; ++ns) {
            acc[0][ns] = MFMA16(aL[0], bH[ns], acc[0][ns]);
            acc[1][ns] = MFMA16(aL[1], bH[ns], acc[1][ns]);
        }
        #pragma unroll
        for (int ns = 0; ns < 4; ++ns) {
            acc[0][ns] = MFMA16(aH[0], bL[ns], acc[0][ns]);
            acc[1][ns] = MFMA16(aH[1], bL[ns], acc[1][ns]);
        }
        __syncthreads();   // LDS reusable (next chunk / epilogue)
    }

    // ---- epilogue: reuse smem as Ts16[128][66] (bf16) or Tf[128][33] (f32) ----
    if (by < 6) {
        unsigned short (*Ts16)[66] = (unsigned short (*)[66])smem;
        #pragma unroll
        for (int ms = 0; ms < 2; ++ms)
            #pragma unroll
            for (int ns = 0; ns < 4; ++ns) {
                const int lc = ns * 16 + m;
                const int col = N0 + lc;
                const float bias = bias_qkv[col];
                const float scale = (col < 128) ? 0.25f : 1.f;
                #pragma unroll
                for (int r = 0; r < 4; ++r) {
                    const int lr = wave * 32 + ms * 16 + q * 4 + r;
                    Ts16[lr][lc] = f2bf((acc[ms][ns][r] + bias) * scale);
                }
            }
        __syncthreads();
        const int qsel = by >> 1, dhalf = by & 1;
        unsigned short* dstH = (qsel == 0) ? QT : (qsel == 1 ? KT : VT);
        // j-major (transposed) for the subplanes attn reads column-wise:
        const bool tr = (qsel == 0) || (br == 1);
        #pragma unroll
        for (int it = 0; it < 4; ++it) {
            int item = it * 256 + t;        // 0..1023: (hh, lr)
            int hh = item >> 7, lr = item & 127;
            u16x8 hi;
            #pragma unroll
            for (int dd = 0; dd < 8; ++dd)
                hi[dd] = Ts16[lr][dd * 8 + hh];
            const size_t sub = ((size_t)(br * 8 + hh) * 2 + dhalf) * NPOS;
            const size_t p16 = tr ? ((size_t)lr * 128 + bx)
                                  : ((size_t)bx * 128 + lr);
            *(u16x8*)(dstH + (sub + p16) * 8) = hi;
        }
    } else {
        float* Tf = (float*)smem;   // [128][33], cols 0..15 used
        #pragma unroll
        for (int ms = 0; ms < 2; ++ms) {
            const float bias = bias_eg[m];
            #pragma unroll
            for (int r = 0; r < 4; ++r) {
                const int lr = wave * 32 + ms * 16 + q * 4 + r;
                Tf[lr * 33 + m] = acc[ms][0][r] + bias;
            }
        }
        __syncthreads();
        // Row p = bx*128 + r128. br=0: dst = p; br=1: dst = r128*128 + bx.
        const int r128 = t & 127, grp = t >> 7;
        const float mk = mask[bx * 128 + r128];
        const int dst = br ? (r128 * 128 + bx) : (bx * 128 + r128);
        if (grp == 0) {
            #pragma unroll
            for (int h = 0; h < 8; ++h)
                Etab[(size_t)(br * 8 + h) * NPOS + dst] =
                    f2bf(Tf[r128 * 33 + h] + mk);
        } else {
            #pragma unroll
            for (int h = 0; h < 8; ++h) {
                const float g = Tf[r128 * 33 + 8 + h] + mk;
                Gtab[(size_t)(br * 8 + h) * NPOS + dst] =
                    f2bf(1.f / (1.f + __expf(-g)));
            }
        }
    }
}

// ---------------- MFMA fused triangle attention (bf16 E/G, hi/lo va out) ----
// grid(1024), 256 thr = 4 waves. Block owns plane = bid>>6, j = (bid&63)*2+it.
// E/G cached in VGPRs across the j-pair. S-column c maps to K-row
// k(c) = (c&15)*8 + (c>>4); softmax is k-permutation invariant and P/V use
// the same order, so the result is exact.
__global__ __launch_bounds__(256) void attn_kernel(
    const unsigned short* __restrict__ QT, const unsigned short* __restrict__ KT,
    const unsigned short* __restrict__ VT,
    const unsigned short* __restrict__ Etab, const unsigned short* __restrict__ Gtab,
    unsigned short* __restrict__ vaH, unsigned short* __restrict__ vaL)
{
    const int bid = blockIdx.x;
    const int plane = bid >> 6;            // 0..15
    const int j0 = (bid & 63) * 2;
    const int t = threadIdx.x;
    const int wave = t >> 6, lane = t & 63;
    const int m = lane & 15, q = lane >> 4;
    const size_t SP = (size_t)NPOS * 8;          // ushorts per sub-plane
    const unsigned short* __restrict__ Eb = Etab + (size_t)plane * NPOS;
    const unsigned short* __restrict__ Gb = Gtab + (size_t)plane * NPOS;

    __shared__ unsigned short Vth[16 * 136];
    __shared__ unsigned short Pl[128 * 136];

    const int strip = wave * 32;

    // E/G register cache (j-independent): 64 VGPR
    u16x8 Ec[2][4], Gc[2][4];
    #pragma unroll
    for (int mt = 0; mt < 2; ++mt)
        #pragma unroll
        for (int r = 0; r < 4; ++r) {
            const int i = strip + mt * 16 + q * 4 + r;
            Ec[mt][r] = *(const u16x8*)(Eb + (size_t)i * 128 + m * 8);
            Gc[mt][r] = *(const u16x8*)(Gb + (size_t)i * 128 + m * 8);
        }

    for (int it = 0; it < 2; ++it) {
        const int j = j0 + it;
        const size_t jb = (size_t)j * 128 * 8;

        // ---- E preload into the MFMA accumulator ----
        f32x4 S[2][8];
        #pragma unroll
        for (int mt = 0; mt < 2; ++mt)
            #pragma unroll
            for (int r = 0; r < 4; ++r) {
                #pragma unroll
                for (int nt = 0; nt < 8; ++nt)
                    S[mt][nt][r] = bf2f(Ec[mt][r][nt]);
            }

        {   // stage V transposed+permuted into LDS: Vth[d*136 + c] = V[k(c)][d]
            int c = t >> 1, ch = t & 1;
            int krow = (c & 15) * 8 + (c >> 4);
            const unsigned short* src = VT + (size_t)(plane * 2 + ch) * SP + jb
                                      + (size_t)krow * 8;
            u16x8 v = *(const u16x8*)src;
            #pragma unroll
            for (int dd = 0; dd < 8; ++dd)
                Vth[(ch * 8 + dd) * 136 + c] = v[dd];
        }

        const bf16x8 zero8 = {};
        const int hf = q & 1;
        const size_t qko = (size_t)(plane * 2 + hf) * SP + jb;

        // Q A-frags (direct from global; q>=2 lanes = zero K-half)
        bf16x8 aQ[2];
        #pragma unroll
        for (int mt = 0; mt < 2; ++mt) {
            const size_t off = qko + (size_t)(strip + mt * 16 + m) * 8;
            aQ[mt] = (q < 2) ? *(const bf16x8*)(QT + off) : zero8;
        }

        // S tiles: B row for tile nt, lane m = K row k = m*8 + nt (permuted)
        #pragma unroll
        for (int nt = 0; nt < 8; ++nt) {
            const size_t koff = qko + (size_t)(m * 8 + nt) * 8;
            bf16x8 bK = (q < 2) ? *(const bf16x8*)(KT + koff) : zero8;
            #pragma unroll
            for (int mt = 0; mt < 2; ++mt)
                S[mt][nt] = MFMA16(aQ[mt], bK, S[mt][nt]);
        }

        // softmax (row cols spread over lanes m: xor 1,2,4,8) + gate + P -> LDS
        #pragma unroll
        for (int mt = 0; mt < 2; ++mt)
            #pragma unroll
            for (int r = 0; r < 4; ++r) {
                float v = -1e30f;
                #pragma unroll
                for (int nt = 0; nt < 8; ++nt) v = fmaxf(v, S[mt][nt][r]);
                v = fmaxf(v, __shfl_xor(v, 1)); v = fmaxf(v, __shfl_xor(v, 2));
                v = fmaxf(v, __shfl_xor(v, 4)); v = fmaxf(v, __shfl_xor(v, 8));
                float s = 0.f;
                #pragma unroll
                for (int nt = 0; nt < 8; ++nt) {
                    float p = __expf(S[mt][nt][r] - v);
                    S[mt][nt][r] = p;
                    s += p;
                }
                s += __shfl_xor(s, 1); s += __shfl_xor(s, 2);
                s += __shfl_xor(s, 4); s += __shfl_xor(s, 8);
                const float inv = 1.f / s;
                const int i = strip + mt * 16 + q * 4 + r;
                #pragma unroll
                for (int nt = 0; nt < 4; ++nt) {
                    Pl[i * 136 + nt * 16 + m] =
                        f2bf(S[mt][nt][r] * inv * bf2f(Gc[mt][r][nt]));
                    Pl[i * 136 + (nt + 4) * 16 + m] =
                        f2bf(S[mt][nt + 4][r] * inv * bf2f(Gc[mt][r][nt + 4]));
                }
            }

        __syncthreads();   // Vth/Pl ready

        // AV = P @ V (both in permuted-k order)
        f32x4 av[2] = {(f32x4){0.f, 0.f, 0.f, 0.f}, (f32x4){0.f, 0.f, 0.f, 0.f}};
        #pragma unroll
        for (int kc = 0; kc < 4; ++kc) {
            const int off = kc * 32 + q * 8;
            bf16x8 bV = *(const bf16x8*)&Vth[m * 136 + off];
            #pragma unroll
            for (int mt = 0; mt < 2; ++mt) {
                bf16x8 aP = *(const bf16x8*)&Pl[(strip + mt * 16 + m) * 136 + off];
                av[mt] = MFMA16(aP, bV, av[mt]);
            }
        }

        // store va' as bf16 hi/lo (row p' = j*128+i, col k' = plane*16 + d)
        #pragma unroll
        for (int mt = 0; mt < 2; ++mt)
            #pragma unroll
            for (int r = 0; r < 4; ++r) {
                const int i = strip + mt * 16 + q * 4 + r;
                const size_t addr = ((size_t)(j * 128 + i)) * 256 + plane * 16 + m;
                const float x = av[mt][r];
                const unsigned short hi = f2bf(x);
                vaH[addr] = hi;
                vaL[addr] = f2bf(x - bf2f(hi));
            }
        __syncthreads();   // LDS reuse across j iterations
    }
}

// ---------------- MFMA GEMM: output projection (va in p'/k' order) ----------
// grid(512), 256 thr. Tile 64(M) x 64(N). K=256; va hi/lo read directly
// (no convert chain). Row-permuted C store.
__global__ __launch_bounds__(256) void gemm_out_kernel(
    const unsigned short* __restrict__ vaH,
    const unsigned short* __restrict__ vaL,
    const unsigned short* __restrict__ B3t,
    const float* __restrict__ bias,
    float* __restrict__ out)
{
    const int t = threadIdx.x;
    const int wave = t >> 6, lane = t & 63;
    const int m = lane & 15, q = lane >> 4;
    const int W0 = (blockIdx.x >> 1) * 64 + wave * 16;
    const int N0 = (blockIdx.x & 1) * 64;

    f32x4 acc[4];
    #pragma unroll
    for (int cc = 0; cc < 4; ++cc) acc[cc] = (f32x4){0.f, 0.f, 0.f, 0.f};

    const unsigned short* arowH = vaH + (size_t)(W0 + m) * 256;
    const unsigned short* arowL = vaL + (size_t)(W0 + m) * 256;
    const unsigned short* bcol[4];
    #pragma unroll
    for (int ns = 0; ns < 4; ++ns)
        bcol[ns] = B3t + (size_t)(N0 + ns * 16 + m) * 256;

    #pragma unroll 2
    for (int kc = 0; kc < 8; ++kc) {
        const int ko = kc * 32 + q * 8;
        bf16x8 ah = *(const bf16x8*)(arowH + ko);
        bf16x8 al = *(const bf16x8*)(arowL + ko);
        bf16x8 bh[4], bl[4];
        #pragma unroll
        for (int ns = 0; ns < 4; ++ns) {
            bh[ns] = *(const bf16x8*)(bcol[ns] + ko);
            bl[ns] = *(const bf16x8*)(bcol[ns] + 128 * 256 + ko);
        }
        #pragma unroll
        for (int ns = 0; ns < 4; ++ns) acc[ns] = MFMA16(ah, bh[ns], acc[ns]);
        #pragma unroll
        for (int ns = 0; ns < 4; ++ns) acc[ns] = MFMA16(al, bh[ns], acc[ns]);
        #pragma unroll
        for (int ns = 0; ns < 4; ++ns) acc[ns] = MFMA16(ah, bl[ns], acc[ns]);
    }

    #pragma unroll
    for (int ns = 0; ns < 4; ++ns) {
        const int col = N0 + ns * 16 + m;
        #pragma unroll
        for (int r = 0; r < 4; ++r) {
            const int prow = W0 + q * 4 + r;                 // p' = j*128+i
            const int orow = ((prow & 127) << 7) | (prow >> 7);  // i*128+j
            out[(size_t)orow * 128 + col] = acc[ns][r] + bias[col];
        }
    }
}

extern "C" void kernel_launch(void* const* d_in, const int* in_sizes, int n_in,
                              void* d_out, int out_size, void* d_ws, size_t ws_size,
                              hipStream_t stream) {
    const float* e        = (const float*)d_in[0];
    const float* mask     = (const float*)d_in[1];
    const float* ln_w     = (const float*)d_in[2];
    const float* ln_b     = (const float*)d_in[3];
    const float* w_qkv_in = (const float*)d_in[4];
    const float* b_qkv_in = (const float*)d_in[5];
    const float* w_eg_in  = (const float*)d_in[6];
    const float* b_eg_in  = (const float*)d_in[7];
    const float* w_qkv_o  = (const float*)d_in[8];
    const float* b_qkv_o  = (const float*)d_in[9];
    const float* w_eg_o   = (const float*)d_in[10];
    const float* b_eg_o   = (const float*)d_in[11];
    const float* w_o      = (const float*)d_in[12];
    const float* b_o      = (const float*)d_in[13];
    float* out = (float*)d_out;

    char* base = (char*)d_ws;
    const size_t PLANE = (size_t)16 * NPOS * 16;                      // ushorts per array
    unsigned short* e_hl = (unsigned short*)base;                     // 8.39 MB
    unsigned short* QT = (unsigned short*)(base + (size_t)NPOS * 256 * 2);
    unsigned short* KT = QT + PLANE;
    unsigned short* VT = KT + PLANE;
    unsigned short* vaH = VT + PLANE;                                 // 8.39 MB
    unsigned short* vaL = vaH + (size_t)NPOS * 256;                   // 8.39 MB
    unsigned short* Etab = vaL + (size_t)NPOS * 256;                  // 0.52 MB (bf16)
    unsigned short* Gtab = Etab + (size_t)16 * NPOS;                  // 0.52 MB
    unsigned short* B3t  = Gtab + (size_t)16 * NPOS;                  // 0.13 MB

    // aliases (lifetime-checked): B1t/B2t overlay vaH (dead before attn writes)
    unsigned short* B1t = vaH;
    unsigned short* B2t = B1t + (size_t)2 * 448 * 128;

    prep_kernel<<<4672, 256, 0, stream>>>(
        e, ln_w, ln_b, e_hl,
        w_qkv_in, w_eg_in, B1t, w_qkv_o, w_eg_o, B2t, w_o, B3t);

    gemm_qkv_kernel<<<dim3(128, 7, 2), 256, 0, stream>>>(
        e_hl, B1t, B2t, b_qkv_in, b_eg_in, b_qkv_o, b_eg_o, mask,
        QT, KT, VT, Etab, Gtab);

    attn_kernel<<<1024, 256, 0, stream>>>(
        QT, KT, VT, Etab, Gtab, vaH, vaL);

    gemm_out_kernel<<<512, 256, 0, stream>>>(vaH, vaL, B3t, b_o, out);
}

// Round 6
// 161.831 us; speedup vs baseline: 3.6035x; 1.1475x over previous
//
#include <hip/hip_runtime.h>
#include <hip/hip_bf16.h>

// B=1, N=128, C=128, H=8, D=16. SCALE=0.25. All I/O fp32.
// GEMMs: bf16 MFMA, split-bf16 hi/lo 3-term for fp32 quality.
// Attention planes are HI-ONLY bf16. Plane arrays: [plane][dhalf][p][8] ushort.
// v12: recovery from r5 regression (attn occupancy collapse at VGPR=148).
//  - attn: v8 grid (2048 blocks, 1 j each), no E/G reg cache,
//    __launch_bounds__(256,4) (VGPR<=128 -> 4 blocks/CU), T14 V-stage split
//    (global load at top, LDS write after softmax), single barrier.
//  - va packed u32 = hi | lo<<16: attn stores 8 dwords/thread (not 16 sub-
//    dword), gemm_out reads half the f32 bytes and unpacks with and/shift.
//  - prep/gemm_qkv unchanged; gemm_out 512 blocks of 64x64.

#define NPOS 16384
#define CDIM 128

typedef __attribute__((ext_vector_type(8))) short bf16x8;
typedef __attribute__((ext_vector_type(8))) unsigned short u16x8;
typedef __attribute__((ext_vector_type(8))) unsigned int u32x8;
typedef __attribute__((ext_vector_type(4))) float f32x4;

#define MFMA16(a, b, c) __builtin_amdgcn_mfma_f32_16x16x32_bf16((a), (b), (c), 0, 0, 0)

#define GLL16(gp, lp) __builtin_amdgcn_global_load_lds( \
    (const __attribute__((address_space(1))) void*)(gp), \
    (__attribute__((address_space(3))) void*)(lp), 16, 0, 0)

static __device__ __forceinline__ unsigned short f2bf(float x) {
    union { float f; unsigned int u; } v; v.f = x;
    unsigned int u = v.u;
    unsigned int r = u + 0x7FFFu + ((u >> 16) & 1u);   // RNE
    return (unsigned short)(r >> 16);
}
static __device__ __forceinline__ float bf2f(unsigned short h) {
    union { float f; unsigned int u; } v; v.u = ((unsigned int)h) << 16; return v.f;
}

// ---------------- prep: LayerNorm + all 3 weight packs, one kernel ---------
// blocks 0..4095: ln (4 rows each); 4096..4319: pack B1t; 4320..4543: pack
// B2t; 4544..4671: pack B3t (w_o, k' = (br*8+h)*16+d ordering).
__global__ __launch_bounds__(256) void prep_kernel(
    const float* __restrict__ e, const float* __restrict__ lnw,
    const float* __restrict__ lnb, unsigned short* __restrict__ e_hl,
    const float* __restrict__ wq1, const float* __restrict__ we1,
    unsigned short* __restrict__ B1t,
    const float* __restrict__ wq2, const float* __restrict__ we2,
    unsigned short* __restrict__ B2t,
    const float* __restrict__ wo, unsigned short* __restrict__ B3t)
{
    const int t = threadIdx.x;
    const int bx = blockIdx.x;
    if (bx < 4096) {
        const int lane = t & 63;
        const int row = bx * 4 + (t >> 6);
        float2 x = *(const float2*)(e + (size_t)row * CDIM + lane * 2);
        float s = x.x + x.y, s2 = x.x * x.x + x.y * x.y;
        #pragma unroll
        for (int off = 1; off < 64; off <<= 1) {
            s  += __shfl_xor(s,  off, 64);
            s2 += __shfl_xor(s2, off, 64);
        }
        float m = s * (1.f / 128.f);
        float v = s2 * (1.f / 128.f) - m * m;
        float sc = rsqrtf(v + 1e-5f);
        float2 wv = *(const float2*)(lnw + lane * 2);
        float2 bv = *(const float2*)(lnb + lane * 2);
        float y0 = (x.x - m) * sc * wv.x + bv.x;
        float y1 = (x.y - m) * sc * wv.y + bv.y;
        unsigned short h0 = f2bf(y0), h1 = f2bf(y1);
        ushort2 hi = {h0, h1};
        ushort2 lo = {f2bf(y0 - bf2f(h0)), f2bf(y1 - bf2f(h1))};
        *(ushort2*)(e_hl + (size_t)row * 256 + lane * 2)       = hi;
        *(ushort2*)(e_hl + (size_t)row * 256 + 128 + lane * 2) = lo;
    } else if (bx < 4544) {
        int pb = bx - 4096;
        const float* wq; const float* we; unsigned short* Bt;
        if (pb < 224) { wq = wq1; we = we1; Bt = B1t; }
        else          { pb -= 224; wq = wq2; we = we2; Bt = B2t; }
        const int idx = pb * 256 + t;    // n*128 + k
        const int n = idx >> 7, k = idx & 127;
        float v = 0.f;
        if (n < 384) v = wq[(size_t)k * 384 + n];
        else if (n < 400) v = we[(size_t)k * 16 + (n - 384)];
        unsigned short hi = f2bf(v);
        Bt[idx] = hi;
        Bt[448 * 128 + idx] = f2bf(v - bf2f(hi));
    } else {
        const int idx = (bx - 4544) * 256 + t;   // n*256 + kp
        const int n = idx >> 8, kp = idx & 255;
        const int d = kp & 15, pl = kp >> 4;
        const int k = d * 16 + pl;
        float v = wo[(size_t)k * 128 + n];
        unsigned short hi = f2bf(v);
        B3t[idx] = hi;
        B3t[128 * 256 + idx] = f2bf(v - bf2f(hi));
    }
}

// ---------------- MFMA GEMM: qkv+eg, global_load_lds staging, fused store --
// grid(128, 7, 2), 256 thr. Tile 128(M) x 64(N). K=128 in 4 chunks.
// LDS: A [hl][q][128 row][16B] 16KB, B [hl][q][64 col][16B] 8KB (aliased by
// the epilogue Ts tile). by 0,1: Q d-halves; 2,3: K; 4,5: V; 6: eg -> tables.
// Subplanes consumed column-wise by attn (Q all br, K/V br=1) are stored
// j-major directly; bx is XCD-chunk swizzled so the 4 blocks sharing a 64B
// output line sit on one XCD's L2.
__global__ __launch_bounds__(256) void gemm_qkv_kernel(
    const unsigned short* __restrict__ e_hl,
    const unsigned short* __restrict__ B1t, const unsigned short* __restrict__ B2t,
    const float* __restrict__ bq_i, const float* __restrict__ be_i,
    const float* __restrict__ bq_o, const float* __restrict__ be_o,
    const float* __restrict__ mask,
    unsigned short* __restrict__ QT, unsigned short* __restrict__ KT,
    unsigned short* __restrict__ VT,
    unsigned short* __restrict__ Etab, unsigned short* __restrict__ Gtab)
{
    __shared__ __align__(16) unsigned char smem[24576];
    unsigned short* Alds = (unsigned short*)smem;            // [2][4][128][8] ushorts
    unsigned short* Blds = (unsigned short*)(smem + 16384);  // [2][4][64][8]

    const int t = threadIdx.x;
    const int wave = t >> 6, lane = t & 63;
    const int m = lane & 15, q = lane >> 4;
    const int c = blockIdx.x;
    const int bx = ((c & 31) << 2) | (c >> 5);   // bx quads share an XCD
    const int W0blk = bx * 128;
    const int by = blockIdx.y;
    const int N0 = by * 64;
    const int br = blockIdx.z;
    const unsigned short* Bt = br ? B2t : B1t;
    const float* bias_qkv = br ? bq_o : bq_i;
    const float* bias_eg  = br ? be_o : be_i;

    f32x4 acc[2][4];
    #pragma unroll
    for (int a = 0; a < 2; ++a)
        #pragma unroll
        for (int cc = 0; cc < 4; ++cc) acc[a][cc] = (f32x4){0.f, 0.f, 0.f, 0.f};

    for (int kc = 0; kc < 4; ++kc) {
        // ---- stage A+B chunk into LDS: 24 wave-instrs, 6 per wave ----
        #pragma unroll
        for (int ii = 0; ii < 6; ++ii) {
            const int id = wave + ii * 4;
            if (id < 16) {
                const int hl = id >> 3, s = id & 7;
                const int qq = s >> 1, rbase = (s & 1) * 64;
                const unsigned short* g = e_hl
                    + (size_t)(W0blk + rbase + lane) * 256 + hl * 128 + kc * 32 + qq * 8;
                unsigned short* l = Alds + hl * 4096 + qq * 1024 + rbase * 8;
                GLL16(g, l);
            } else {
                const int id2 = id - 16;
                const int hl = id2 >> 2, qq = id2 & 3;
                const unsigned short* g = Bt + (size_t)(N0 + lane) * 128
                    + hl * (448 * 128) + kc * 32 + qq * 8;
                unsigned short* l = Blds + hl * 2048 + qq * 512;
                GLL16(g, l);
            }
        }
        __syncthreads();   // drains vmcnt: staged data visible

        bf16x8 aH[2], aL[2], bH[4], bL[4];
        #pragma unroll
        for (int ms = 0; ms < 2; ++ms) {
            const int row = wave * 32 + ms * 16 + m;
            aH[ms] = *(const bf16x8*)(Alds + 0    + q * 1024 + row * 8);
            aL[ms] = *(const bf16x8*)(Alds + 4096 + q * 1024 + row * 8);
        }
        #pragma unroll
        for (int ns = 0; ns < 4; ++ns) {
            bH[ns] = *(const bf16x8*)(Blds + 0    + q * 512 + (ns * 16 + m) * 8);
            bL[ns] = *(const bf16x8*)(Blds + 2048 + q * 512 + (ns * 16 + m) * 8);
        }
        #pragma unroll
        for (int ns = 0; ns < 4; ++ns) {
            acc[0][ns] = MFMA16(aH[0], bH[ns], acc[0][ns]);
            acc[1][ns] = MFMA16(aH[1], bH[ns], acc[1][ns]);
        }
        #pragma unroll
        for (int ns = 0; ns < 4; ++ns) {
            acc[0][ns] = MFMA16(aL[0], bH[ns], acc[0][ns]);
            acc[1][ns] = MFMA16(aL[1], bH[ns], acc[1][ns]);
        }
        #pragma unroll
        for (int ns = 0; ns < 4; ++ns) {
            acc[0][ns] = MFMA16(aH[0], bL[ns], acc[0][ns]);
            acc[1][ns] = MFMA16(aH[1], bL[ns], acc[1][ns]);
        }
        __syncthreads();   // LDS reusable (next chunk / epilogue)
    }

    // ---- epilogue: reuse smem as Ts16[128][66] (bf16) or Tf[128][33] (f32) ----
    if (by < 6) {
        unsigned short (*Ts16)[66] = (unsigned short (*)[66])smem;
        #pragma unroll
        for (int ms = 0; ms < 2; ++ms)
            #pragma unroll
            for (int ns = 0; ns < 4; ++ns) {
                const int lc = ns * 16 + m;
                const int col = N0 + lc;
                const float bias = bias_qkv[col];
                const float scale = (col < 128) ? 0.25f : 1.f;
                #pragma unroll
                for (int r = 0; r < 4; ++r) {
                    const int lr = wave * 32 + ms * 16 + q * 4 + r;
                    Ts16[lr][lc] = f2bf((acc[ms][ns][r] + bias) * scale);
                }
            }
        __syncthreads();
        const int qsel = by >> 1, dhalf = by & 1;
        unsigned short* dstH = (qsel == 0) ? QT : (qsel == 1 ? KT : VT);
        // j-major (transposed) for the subplanes attn reads column-wise:
        const bool tr = (qsel == 0) || (br == 1);
        #pragma unroll
        for (int it = 0; it < 4; ++it) {
            int item = it * 256 + t;        // 0..1023: (hh, lr)
            int hh = item >> 7, lr = item & 127;
            u16x8 hi;
            #pragma unroll
            for (int dd = 0; dd < 8; ++dd)
                hi[dd] = Ts16[lr][dd * 8 + hh];
            const size_t sub = ((size_t)(br * 8 + hh) * 2 + dhalf) * NPOS;
            const size_t p16 = tr ? ((size_t)lr * 128 + bx)
                                  : ((size_t)bx * 128 + lr);
            *(u16x8*)(dstH + (sub + p16) * 8) = hi;
        }
    } else {
        float* Tf = (float*)smem;   // [128][33], cols 0..15 used
        #pragma unroll
        for (int ms = 0; ms < 2; ++ms) {
            const float bias = bias_eg[m];
            #pragma unroll
            for (int r = 0; r < 4; ++r) {
                const int lr = wave * 32 + ms * 16 + q * 4 + r;
                Tf[lr * 33 + m] = acc[ms][0][r] + bias;
            }
        }
        __syncthreads();
        // Row p = bx*128 + r128. br=0: dst = p; br=1: dst = r128*128 + bx.
        const int r128 = t & 127, grp = t >> 7;
        const float mk = mask[bx * 128 + r128];
        const int dst = br ? (r128 * 128 + bx) : (bx * 128 + r128);
        if (grp == 0) {
            #pragma unroll
            for (int h = 0; h < 8; ++h)
                Etab[(size_t)(br * 8 + h) * NPOS + dst] =
                    f2bf(Tf[r128 * 33 + h] + mk);
        } else {
            #pragma unroll
            for (int h = 0; h < 8; ++h) {
                const float g = Tf[r128 * 33 + 8 + h] + mk;
                Gtab[(size_t)(br * 8 + h) * NPOS + dst] =
                    f2bf(1.f / (1.f + __expf(-g)));
            }
        }
    }
}

// ---------------- MFMA fused triangle attention (bf16 E/G, packed-u32 va) ---
// grid (j=128, h=8, br=2), 256 thr = 4 waves, wave owns 32-row strip.
// 4 blocks/CU (VGPR<=128 via launch_bounds, LDS 39.2KB). T14 V-stage split:
// V global load issued at top, LDS write after softmax. S-column c maps to
// K-row k(c) = (c&15)*8 + (c>>4); softmax is k-permutation invariant and P/V
// use the same order, so the result is exact.
__global__ __launch_bounds__(256, 4) void attn_kernel(
    const unsigned short* __restrict__ QT, const unsigned short* __restrict__ KT,
    const unsigned short* __restrict__ VT,
    const unsigned short* __restrict__ Etab, const unsigned short* __restrict__ Gtab,
    unsigned int* __restrict__ vaP)
{
    const int j = blockIdx.x, h = blockIdx.y, br = blockIdx.z;
    const int t = threadIdx.x;
    const int wave = t >> 6, lane = t & 63;
    const int m = lane & 15, q = lane >> 4;
    const int plane = br * 8 + h;
    const size_t SP = (size_t)NPOS * 8;          // ushorts per sub-plane
    const size_t jb = (size_t)j * 128 * 8;
    const unsigned short* __restrict__ Eb = Etab + (size_t)plane * NPOS;
    const unsigned short* __restrict__ Gb = Gtab + (size_t)plane * NPOS;

    __shared__ unsigned short Vth[16 * 136];
    __shared__ unsigned short Pl[128 * 136];

    const int strip = wave * 32;

    // ---- T14: issue V global load FIRST (write to LDS deferred) ----
    const int vc = t >> 1, vch = t & 1;
    const int vkrow = (vc & 15) * 8 + (vc >> 4);
    const u16x8 vv = *(const u16x8*)(VT + (size_t)(plane * 2 + vch) * SP + jb
                                     + (size_t)vkrow * 8);

    // ---- E preload into the MFMA accumulator ----
    f32x4 S[2][8];
    #pragma unroll
    for (int mt = 0; mt < 2; ++mt)
        #pragma unroll
        for (int r = 0; r < 4; ++r) {
            const int i = strip + mt * 16 + q * 4 + r;
            u16x8 ev = *(const u16x8*)(Eb + (size_t)i * 128 + m * 8);
            #pragma unroll
            for (int nt = 0; nt < 8; ++nt) S[mt][nt][r] = bf2f(ev[nt]);
        }

    const bf16x8 zero8 = {};
    const int hf = q & 1;
    const size_t qko = (size_t)(plane * 2 + hf) * SP + jb;

    // Q A-frags (direct from global; q>=2 lanes = zero K-half)
    bf16x8 aQ[2];
    #pragma unroll
    for (int mt = 0; mt < 2; ++mt) {
        const size_t off = qko + (size_t)(strip + mt * 16 + m) * 8;
        aQ[mt] = (q < 2) ? *(const bf16x8*)(QT + off) : zero8;
    }

    // S tiles: B row for tile nt, lane m = K row k = m*8 + nt (permuted)
    #pragma unroll
    for (int nt = 0; nt < 8; ++nt) {
        const size_t koff = qko + (size_t)(m * 8 + nt) * 8;
        bf16x8 bK = (q < 2) ? *(const bf16x8*)(KT + koff) : zero8;
        #pragma unroll
        for (int mt = 0; mt < 2; ++mt)
            S[mt][nt] = MFMA16(aQ[mt], bK, S[mt][nt]);
    }

    // softmax (row cols spread over lanes m: xor 1,2,4,8) + gate + P -> LDS
    #pragma unroll
    for (int mt = 0; mt < 2; ++mt)
        #pragma unroll
        for (int r = 0; r < 4; ++r) {
            float v = -1e30f;
            #pragma unroll
            for (int nt = 0; nt < 8; ++nt) v = fmaxf(v, S[mt][nt][r]);
            v = fmaxf(v, __shfl_xor(v, 1)); v = fmaxf(v, __shfl_xor(v, 2));
            v = fmaxf(v, __shfl_xor(v, 4)); v = fmaxf(v, __shfl_xor(v, 8));
            float s = 0.f;
            #pragma unroll
            for (int nt = 0; nt < 8; ++nt) {
                float p = __expf(S[mt][nt][r] - v);
                S[mt][nt][r] = p;
                s += p;
            }
            s += __shfl_xor(s, 1); s += __shfl_xor(s, 2);
            s += __shfl_xor(s, 4); s += __shfl_xor(s, 8);
            const float inv = 1.f / s;
            const int i = strip + mt * 16 + q * 4 + r;
            u16x8 gv = *(const u16x8*)(Gb + (size_t)i * 128 + m * 8);
            #pragma unroll
            for (int nt = 0; nt < 4; ++nt) {
                Pl[i * 136 + nt * 16 + m] =
                    f2bf(S[mt][nt][r] * inv * bf2f(gv[nt]));
                Pl[i * 136 + (nt + 4) * 16 + m] =
                    f2bf(S[mt][nt + 4][r] * inv * bf2f(gv[nt + 4]));
            }
        }

    // ---- T14: deferred V write to LDS: Vth[d*136 + c] = V[k(c)][d] ----
    #pragma unroll
    for (int dd = 0; dd < 8; ++dd)
        Vth[(vch * 8 + dd) * 136 + vc] = vv[dd];

    __syncthreads();   // Vth/Pl ready

    // AV = P @ V (both in permuted-k order)
    f32x4 av[2] = {(f32x4){0.f, 0.f, 0.f, 0.f}, (f32x4){0.f, 0.f, 0.f, 0.f}};
    #pragma unroll
    for (int kc = 0; kc < 4; ++kc) {
        const int off = kc * 32 + q * 8;
        bf16x8 bV = *(const bf16x8*)&Vth[m * 136 + off];
        #pragma unroll
        for (int mt = 0; mt < 2; ++mt) {
            bf16x8 aP = *(const bf16x8*)&Pl[(strip + mt * 16 + m) * 136 + off];
            av[mt] = MFMA16(aP, bV, av[mt]);
        }
    }

    // store va' packed u32 (hi | lo<<16), row p' = j*128+i, col plane*16+d:
    // 8 dword stores/thread, 64B per 16 lanes.
    #pragma unroll
    for (int mt = 0; mt < 2; ++mt)
        #pragma unroll
        for (int r = 0; r < 4; ++r) {
            const int i = strip + mt * 16 + q * 4 + r;
            const size_t addr = ((size_t)(j * 128 + i)) * 256 + plane * 16 + m;
            const float x = av[mt][r];
            const unsigned short hi = f2bf(x);
            const unsigned short lo = f2bf(x - bf2f(hi));
            vaP[addr] = (unsigned int)hi | ((unsigned int)lo << 16);
        }
}

// ---------------- MFMA GEMM: output projection (va in p'/k' order) ----------
// grid(512), 256 thr. Tile 64(M) x 64(N). K=256; packed-u32 va unpacked with
// and/shift (bit-identical hi/lo). Row-permuted C store.
__global__ __launch_bounds__(256) void gemm_out_kernel(
    const unsigned int* __restrict__ vaP,
    const unsigned short* __restrict__ B3t,
    const float* __restrict__ bias,
    float* __restrict__ out)
{
    const int t = threadIdx.x;
    const int wave = t >> 6, lane = t & 63;
    const int m = lane & 15, q = lane >> 4;
    const int W0 = (blockIdx.x >> 1) * 64 + wave * 16;
    const int N0 = (blockIdx.x & 1) * 64;

    f32x4 acc[4];
    #pragma unroll
    for (int cc = 0; cc < 4; ++cc) acc[cc] = (f32x4){0.f, 0.f, 0.f, 0.f};

    const unsigned int* arow = vaP + (size_t)(W0 + m) * 256;
    const unsigned short* bcol[4];
    #pragma unroll
    for (int ns = 0; ns < 4; ++ns)
        bcol[ns] = B3t + (size_t)(N0 + ns * 16 + m) * 256;

    #pragma unroll 2
    for (int kc = 0; kc < 8; ++kc) {
        const int ko = kc * 32 + q * 8;
        u32x8 w = *(const u32x8*)(arow + ko);
        bf16x8 ah, al;
        #pragma unroll
        for (int jj = 0; jj < 8; ++jj) {
            ah[jj] = (short)(w[jj] & 0xffffu);
            al[jj] = (short)(w[jj] >> 16);
        }
        bf16x8 bh[4], bl[4];
        #pragma unroll
        for (int ns = 0; ns < 4; ++ns) {
            bh[ns] = *(const bf16x8*)(bcol[ns] + ko);
            bl[ns] = *(const bf16x8*)(bcol[ns] + 128 * 256 + ko);
        }
        #pragma unroll
        for (int ns = 0; ns < 4; ++ns) acc[ns] = MFMA16(ah, bh[ns], acc[ns]);
        #pragma unroll
        for (int ns = 0; ns < 4; ++ns) acc[ns] = MFMA16(al, bh[ns], acc[ns]);
        #pragma unroll
        for (int ns = 0; ns < 4; ++ns) acc[ns] = MFMA16(ah, bl[ns], acc[ns]);
    }

    #pragma unroll
    for (int ns = 0; ns < 4; ++ns) {
        const int col = N0 + ns * 16 + m;
        #pragma unroll
        for (int r = 0; r < 4; ++r) {
            const int prow = W0 + q * 4 + r;                 // p' = j*128+i
            const int orow = ((prow & 127) << 7) | (prow >> 7);  // i*128+j
            out[(size_t)orow * 128 + col] = acc[ns][r] + bias[col];
        }
    }
}

extern "C" void kernel_launch(void* const* d_in, const int* in_sizes, int n_in,
                              void* d_out, int out_size, void* d_ws, size_t ws_size,
                              hipStream_t stream) {
    const float* e        = (const float*)d_in[0];
    const float* mask     = (const float*)d_in[1];
    const float* ln_w     = (const float*)d_in[2];
    const float* ln_b     = (const float*)d_in[3];
    const float* w_qkv_in = (const float*)d_in[4];
    const float* b_qkv_in = (const float*)d_in[5];
    const float* w_eg_in  = (const float*)d_in[6];
    const float* b_eg_in  = (const float*)d_in[7];
    const float* w_qkv_o  = (const float*)d_in[8];
    const float* b_qkv_o  = (const float*)d_in[9];
    const float* w_eg_o   = (const float*)d_in[10];
    const float* b_eg_o   = (const float*)d_in[11];
    const float* w_o      = (const float*)d_in[12];
    const float* b_o      = (const float*)d_in[13];
    float* out = (float*)d_out;

    char* base = (char*)d_ws;
    const size_t PLANE = (size_t)16 * NPOS * 16;                      // ushorts per array
    unsigned short* e_hl = (unsigned short*)base;                     // 8.39 MB
    unsigned short* QT = (unsigned short*)(base + (size_t)NPOS * 256 * 2);
    unsigned short* KT = QT + PLANE;
    unsigned short* VT = KT + PLANE;
    unsigned int* vaP = (unsigned int*)(VT + PLANE);                  // 16.78 MB
    unsigned short* Etab = (unsigned short*)(vaP + (size_t)NPOS * 256);// 0.52 MB (bf16)
    unsigned short* Gtab = Etab + (size_t)16 * NPOS;                  // 0.52 MB
    unsigned short* B3t  = Gtab + (size_t)16 * NPOS;                  // 0.13 MB

    // aliases (lifetime-checked): B1t/B2t overlay vaP (dead before attn writes)
    unsigned short* B1t = (unsigned short*)vaP;
    unsigned short* B2t = B1t + (size_t)2 * 448 * 128;

    prep_kernel<<<4672, 256, 0, stream>>>(
        e, ln_w, ln_b, e_hl,
        w_qkv_in, w_eg_in, B1t, w_qkv_o, w_eg_o, B2t, w_o, B3t);

    gemm_qkv_kernel<<<dim3(128, 7, 2), 256, 0, stream>>>(
        e_hl, B1t, B2t, b_qkv_in, b_eg_in, b_qkv_o, b_eg_o, mask,
        QT, KT, VT, Etab, Gtab);

    attn_kernel<<<dim3(128, 8, 2), 256, 0, stream>>>(
        QT, KT, VT, Etab, Gtab, vaP);

    gemm_out_kernel<<<512, 256, 0, stream>>>(vaP, B3t, b_o, out);
}

// Round 7
// 160.440 us; speedup vs baseline: 3.6348x; 1.0087x over previous
//
#include <hip/hip_runtime.h>
#include <hip/hip_bf16.h>

// B=1, N=128, C=128, H=8, D=16. SCALE=0.25. All I/O fp32.
// GEMMs: bf16 MFMA, split-bf16 hi/lo 3-term for fp32 quality.
// Attention planes are HI-ONLY bf16. Plane arrays: [plane][dhalf][p][8] ushort.
// v13 = v12 + gemm_qkv N-merge: 128x128 tiles for Q/K/V (by 0..2), eg keeps
// the 64-wide path (by 3). Grid 1792 -> 1024 blocks; e_hl re-reads 14x -> 8x
// (staged traffic 172 -> 123 MB). FMA order per output unchanged ->
// bit-identical results. attn/gemm_out/prep unchanged from v12.

#define NPOS 16384
#define CDIM 128

typedef __attribute__((ext_vector_type(8))) short bf16x8;
typedef __attribute__((ext_vector_type(8))) unsigned short u16x8;
typedef __attribute__((ext_vector_type(8))) unsigned int u32x8;
typedef __attribute__((ext_vector_type(4))) float f32x4;

#define MFMA16(a, b, c) __builtin_amdgcn_mfma_f32_16x16x32_bf16((a), (b), (c), 0, 0, 0)

#define GLL16(gp, lp) __builtin_amdgcn_global_load_lds( \
    (const __attribute__((address_space(1))) void*)(gp), \
    (__attribute__((address_space(3))) void*)(lp), 16, 0, 0)

static __device__ __forceinline__ unsigned short f2bf(float x) {
    union { float f; unsigned int u; } v; v.f = x;
    unsigned int u = v.u;
    unsigned int r = u + 0x7FFFu + ((u >> 16) & 1u);   // RNE
    return (unsigned short)(r >> 16);
}
static __device__ __forceinline__ float bf2f(unsigned short h) {
    union { float f; unsigned int u; } v; v.u = ((unsigned int)h) << 16; return v.f;
}

// ---------------- prep: LayerNorm + all 3 weight packs, one kernel ---------
// blocks 0..4095: ln (4 rows each); 4096..4319: pack B1t; 4320..4543: pack
// B2t; 4544..4671: pack B3t (w_o, k' = (br*8+h)*16+d ordering).
__global__ __launch_bounds__(256) void prep_kernel(
    const float* __restrict__ e, const float* __restrict__ lnw,
    const float* __restrict__ lnb, unsigned short* __restrict__ e_hl,
    const float* __restrict__ wq1, const float* __restrict__ we1,
    unsigned short* __restrict__ B1t,
    const float* __restrict__ wq2, const float* __restrict__ we2,
    unsigned short* __restrict__ B2t,
    const float* __restrict__ wo, unsigned short* __restrict__ B3t)
{
    const int t = threadIdx.x;
    const int bx = blockIdx.x;
    if (bx < 4096) {
        const int lane = t & 63;
        const int row = bx * 4 + (t >> 6);
        float2 x = *(const float2*)(e + (size_t)row * CDIM + lane * 2);
        float s = x.x + x.y, s2 = x.x * x.x + x.y * x.y;
        #pragma unroll
        for (int off = 1; off < 64; off <<= 1) {
            s  += __shfl_xor(s,  off, 64);
            s2 += __shfl_xor(s2, off, 64);
        }
        float m = s * (1.f / 128.f);
        float v = s2 * (1.f / 128.f) - m * m;
        float sc = rsqrtf(v + 1e-5f);
        float2 wv = *(const float2*)(lnw + lane * 2);
        float2 bv = *(const float2*)(lnb + lane * 2);
        float y0 = (x.x - m) * sc * wv.x + bv.x;
        float y1 = (x.y - m) * sc * wv.y + bv.y;
        unsigned short h0 = f2bf(y0), h1 = f2bf(y1);
        ushort2 hi = {h0, h1};
        ushort2 lo = {f2bf(y0 - bf2f(h0)), f2bf(y1 - bf2f(h1))};
        *(ushort2*)(e_hl + (size_t)row * 256 + lane * 2)       = hi;
        *(ushort2*)(e_hl + (size_t)row * 256 + 128 + lane * 2) = lo;
    } else if (bx < 4544) {
        int pb = bx - 4096;
        const float* wq; const float* we; unsigned short* Bt;
        if (pb < 224) { wq = wq1; we = we1; Bt = B1t; }
        else          { pb -= 224; wq = wq2; we = we2; Bt = B2t; }
        const int idx = pb * 256 + t;    // n*128 + k
        const int n = idx >> 7, k = idx & 127;
        float v = 0.f;
        if (n < 384) v = wq[(size_t)k * 384 + n];
        else if (n < 400) v = we[(size_t)k * 16 + (n - 384)];
        unsigned short hi = f2bf(v);
        Bt[idx] = hi;
        Bt[448 * 128 + idx] = f2bf(v - bf2f(hi));
    } else {
        const int idx = (bx - 4544) * 256 + t;   // n*256 + kp
        const int n = idx >> 8, kp = idx & 255;
        const int d = kp & 15, pl = kp >> 4;
        const int k = d * 16 + pl;
        float v = wo[(size_t)k * 128 + n];
        unsigned short hi = f2bf(v);
        B3t[idx] = hi;
        B3t[128 * 256 + idx] = f2bf(v - bf2f(hi));
    }
}

// ---------------- MFMA GEMM: qkv+eg, global_load_lds staging, fused store --
// grid(128, 4, 2), 256 thr. by 0..2: tile 128(M) x 128(N) (Q, K, V); by 3:
// tile 128 x 64 (eg -> tables). K=128 in 4 chunks, single-buffered LDS:
// A [hl][qq][128 row][8] 16KB + B [hl][qq][128 col][8] 16KB (by<3).
// Epilogue reuses smem as Ts16[128][130]. Subplanes consumed column-wise by
// attn (Q all br, K/V br=1) stored j-major; bx XCD-quad swizzled.
__global__ __launch_bounds__(256) void gemm_qkv_kernel(
    const unsigned short* __restrict__ e_hl,
    const unsigned short* __restrict__ B1t, const unsigned short* __restrict__ B2t,
    const float* __restrict__ bq_i, const float* __restrict__ be_i,
    const float* __restrict__ bq_o, const float* __restrict__ be_o,
    const float* __restrict__ mask,
    unsigned short* __restrict__ QT, unsigned short* __restrict__ KT,
    unsigned short* __restrict__ VT,
    unsigned short* __restrict__ Etab, unsigned short* __restrict__ Gtab)
{
    __shared__ __align__(16) unsigned char smem[33792];
    unsigned short* Alds = (unsigned short*)smem;            // [2][4][128][8] ushorts
    unsigned short* Blds = (unsigned short*)(smem + 16384);

    const int t = threadIdx.x;
    const int wave = t >> 6, lane = t & 63;
    const int m = lane & 15, q = lane >> 4;
    const int c = blockIdx.x;
    const int bx = ((c & 31) << 2) | (c >> 5);   // bx quads share an XCD
    const int W0blk = bx * 128;
    const int by = blockIdx.y;
    const int br = blockIdx.z;
    const unsigned short* Bt = br ? B2t : B1t;
    const float* bias_qkv = br ? bq_o : bq_i;
    const float* bias_eg  = br ? be_o : be_i;

    if (by < 3) {
        // ================= 128x128 Q/K/V tile =================
        const int N0 = by * 128;
        f32x4 acc[2][8];
        #pragma unroll
        for (int a = 0; a < 2; ++a)
            #pragma unroll
            for (int cc = 0; cc < 8; ++cc) acc[a][cc] = (f32x4){0.f, 0.f, 0.f, 0.f};

        for (int kc = 0; kc < 4; ++kc) {
            // stage A+B chunk: 32 wave-instrs, 8 per wave
            #pragma unroll
            for (int ii = 0; ii < 8; ++ii) {
                const int id = wave + ii * 4;        // 0..31, each once
                const int hl = (id >> 3) & 1;
                const int s = id & 7;
                const int qq = s >> 1, rbase = (s & 1) * 64;
                if (id < 16) {
                    const unsigned short* g = e_hl
                        + (size_t)(W0blk + rbase + lane) * 256 + hl * 128 + kc * 32 + qq * 8;
                    unsigned short* l = Alds + hl * 4096 + qq * 1024 + rbase * 8;
                    GLL16(g, l);
                } else {
                    const unsigned short* g = Bt + (size_t)(N0 + rbase + lane) * 128
                        + hl * (448 * 128) + kc * 32 + qq * 8;
                    unsigned short* l = Blds + hl * 4096 + qq * 1024 + rbase * 8;
                    GLL16(g, l);
                }
            }
            __syncthreads();   // drains vmcnt: staged data visible

            bf16x8 aH[2], aL[2];
            #pragma unroll
            for (int ms = 0; ms < 2; ++ms) {
                const int row = wave * 32 + ms * 16 + m;
                aH[ms] = *(const bf16x8*)(Alds + 0    + q * 1024 + row * 8);
                aL[ms] = *(const bf16x8*)(Alds + 4096 + q * 1024 + row * 8);
            }
            #pragma unroll
            for (int half = 0; half < 2; ++half) {
                bf16x8 bH[4], bL[4];
                #pragma unroll
                for (int ns = 0; ns < 4; ++ns) {
                    const int cc = (half * 4 + ns) * 16 + m;
                    bH[ns] = *(const bf16x8*)(Blds + 0    + q * 1024 + cc * 8);
                    bL[ns] = *(const bf16x8*)(Blds + 4096 + q * 1024 + cc * 8);
                }
                #pragma unroll
                for (int ns = 0; ns < 4; ++ns) {
                    const int nt = half * 4 + ns;
                    acc[0][nt] = MFMA16(aH[0], bH[ns], acc[0][nt]);
                    acc[1][nt] = MFMA16(aH[1], bH[ns], acc[1][nt]);
                }
                #pragma unroll
                for (int ns = 0; ns < 4; ++ns) {
                    const int nt = half * 4 + ns;
                    acc[0][nt] = MFMA16(aL[0], bH[ns], acc[0][nt]);
                    acc[1][nt] = MFMA16(aL[1], bH[ns], acc[1][nt]);
                }
                #pragma unroll
                for (int ns = 0; ns < 4; ++ns) {
                    const int nt = half * 4 + ns;
                    acc[0][nt] = MFMA16(aH[0], bL[ns], acc[0][nt]);
                    acc[1][nt] = MFMA16(aH[1], bL[ns], acc[1][nt]);
                }
            }
            __syncthreads();   // LDS reusable (next chunk / epilogue)
        }

        // epilogue: Ts16[128][130], both d-halves
        unsigned short (*Ts16)[130] = (unsigned short (*)[130])smem;
        #pragma unroll
        for (int ms = 0; ms < 2; ++ms)
            #pragma unroll
            for (int nt = 0; nt < 8; ++nt) {
                const int lc = nt * 16 + m;
                const int col = N0 + lc;
                const float bias = bias_qkv[col];
                const float scale = (col < 128) ? 0.25f : 1.f;
                #pragma unroll
                for (int r = 0; r < 4; ++r) {
                    const int lr = wave * 32 + ms * 16 + q * 4 + r;
                    Ts16[lr][lc] = f2bf((acc[ms][nt][r] + bias) * scale);
                }
            }
        __syncthreads();
        unsigned short* dstH = (by == 0) ? QT : (by == 1 ? KT : VT);
        // j-major (transposed) for the subplanes attn reads column-wise:
        const bool tr = (by == 0) || (br == 1);
        #pragma unroll
        for (int it = 0; it < 8; ++it) {
            int item = it * 256 + t;        // 0..2047: (hh, dhalf, lr)
            int hh = item >> 8;
            int dhalf = (item >> 7) & 1;
            int lr = item & 127;
            u16x8 hi;
            #pragma unroll
            for (int dd = 0; dd < 8; ++dd)
                hi[dd] = Ts16[lr][dhalf * 64 + dd * 8 + hh];
            const size_t sub = ((size_t)(br * 8 + hh) * 2 + dhalf) * NPOS;
            const size_t p16 = tr ? ((size_t)lr * 128 + bx)
                                  : ((size_t)bx * 128 + lr);
            *(u16x8*)(dstH + (sub + p16) * 8) = hi;
        }
    } else {
        // ================= 128x64 eg tile -> tables =================
        const int N0 = 384;
        f32x4 acc[2][4];
        #pragma unroll
        for (int a = 0; a < 2; ++a)
            #pragma unroll
            for (int cc = 0; cc < 4; ++cc) acc[a][cc] = (f32x4){0.f, 0.f, 0.f, 0.f};

        for (int kc = 0; kc < 4; ++kc) {
            #pragma unroll
            for (int ii = 0; ii < 6; ++ii) {
                const int id = wave + ii * 4;
                if (id < 16) {
                    const int hl = id >> 3, s = id & 7;
                    const int qq = s >> 1, rbase = (s & 1) * 64;
                    const unsigned short* g = e_hl
                        + (size_t)(W0blk + rbase + lane) * 256 + hl * 128 + kc * 32 + qq * 8;
                    unsigned short* l = Alds + hl * 4096 + qq * 1024 + rbase * 8;
                    GLL16(g, l);
                } else {
                    const int id2 = id - 16;
                    const int hl = id2 >> 2, qq = id2 & 3;
                    const unsigned short* g = Bt + (size_t)(N0 + lane) * 128
                        + hl * (448 * 128) + kc * 32 + qq * 8;
                    unsigned short* l = Blds + hl * 2048 + qq * 512;
                    GLL16(g, l);
                }
            }
            __syncthreads();

            bf16x8 aH[2], aL[2], bH[4], bL[4];
            #pragma unroll
            for (int ms = 0; ms < 2; ++ms) {
                const int row = wave * 32 + ms * 16 + m;
                aH[ms] = *(const bf16x8*)(Alds + 0    + q * 1024 + row * 8);
                aL[ms] = *(const bf16x8*)(Alds + 4096 + q * 1024 + row * 8);
            }
            #pragma unroll
            for (int ns = 0; ns < 4; ++ns) {
                bH[ns] = *(const bf16x8*)(Blds + 0    + q * 512 + (ns * 16 + m) * 8);
                bL[ns] = *(const bf16x8*)(Blds + 2048 + q * 512 + (ns * 16 + m) * 8);
            }
            #pragma unroll
            for (int ns = 0; ns < 4; ++ns) {
                acc[0][ns] = MFMA16(aH[0], bH[ns], acc[0][ns]);
                acc[1][ns] = MFMA16(aH[1], bH[ns], acc[1][ns]);
            }
            #pragma unroll
            for (int ns = 0; ns < 4; ++ns) {
                acc[0][ns] = MFMA16(aL[0], bH[ns], acc[0][ns]);
                acc[1][ns] = MFMA16(aL[1], bH[ns], acc[1][ns]);
            }
            #pragma unroll
            for (int ns = 0; ns < 4; ++ns) {
                acc[0][ns] = MFMA16(aH[0], bL[ns], acc[0][ns]);
                acc[1][ns] = MFMA16(aH[1], bL[ns], acc[1][ns]);
            }
            __syncthreads();
        }

        float* Tf = (float*)smem;   // [128][33], cols 0..15 used
        #pragma unroll
        for (int ms = 0; ms < 2; ++ms) {
            const float bias = bias_eg[m];
            #pragma unroll
            for (int r = 0; r < 4; ++r) {
                const int lr = wave * 32 + ms * 16 + q * 4 + r;
                Tf[lr * 33 + m] = acc[ms][0][r] + bias;
            }
        }
        __syncthreads();
        // Row p = bx*128 + r128. br=0: dst = p; br=1: dst = r128*128 + bx.
        const int r128 = t & 127, grp = t >> 7;
        const float mk = mask[bx * 128 + r128];
        const int dst = br ? (r128 * 128 + bx) : (bx * 128 + r128);
        if (grp == 0) {
            #pragma unroll
            for (int h = 0; h < 8; ++h)
                Etab[(size_t)(br * 8 + h) * NPOS + dst] =
                    f2bf(Tf[r128 * 33 + h] + mk);
        } else {
            #pragma unroll
            for (int h = 0; h < 8; ++h) {
                const float g = Tf[r128 * 33 + 8 + h] + mk;
                Gtab[(size_t)(br * 8 + h) * NPOS + dst] =
                    f2bf(1.f / (1.f + __expf(-g)));
            }
        }
    }
}

// ---------------- MFMA fused triangle attention (bf16 E/G, packed-u32 va) ---
// grid (j=128, h=8, br=2), 256 thr = 4 waves, wave owns 32-row strip.
// 4 blocks/CU (VGPR<=128 via launch_bounds, LDS 39.2KB). T14 V-stage split:
// V global load issued at top, LDS write after softmax. S-column c maps to
// K-row k(c) = (c&15)*8 + (c>>4); softmax is k-permutation invariant and P/V
// use the same order, so the result is exact.
__global__ __launch_bounds__(256, 4) void attn_kernel(
    const unsigned short* __restrict__ QT, const unsigned short* __restrict__ KT,
    const unsigned short* __restrict__ VT,
    const unsigned short* __restrict__ Etab, const unsigned short* __restrict__ Gtab,
    unsigned int* __restrict__ vaP)
{
    const int j = blockIdx.x, h = blockIdx.y, br = blockIdx.z;
    const int t = threadIdx.x;
    const int wave = t >> 6, lane = t & 63;
    const int m = lane & 15, q = lane >> 4;
    const int plane = br * 8 + h;
    const size_t SP = (size_t)NPOS * 8;          // ushorts per sub-plane
    const size_t jb = (size_t)j * 128 * 8;
    const unsigned short* __restrict__ Eb = Etab + (size_t)plane * NPOS;
    const unsigned short* __restrict__ Gb = Gtab + (size_t)plane * NPOS;

    __shared__ unsigned short Vth[16 * 136];
    __shared__ unsigned short Pl[128 * 136];

    const int strip = wave * 32;

    // ---- T14: issue V global load FIRST (write to LDS deferred) ----
    const int vc = t >> 1, vch = t & 1;
    const int vkrow = (vc & 15) * 8 + (vc >> 4);
    const u16x8 vv = *(const u16x8*)(VT + (size_t)(plane * 2 + vch) * SP + jb
                                     + (size_t)vkrow * 8);

    // ---- E preload into the MFMA accumulator ----
    f32x4 S[2][8];
    #pragma unroll
    for (int mt = 0; mt < 2; ++mt)
        #pragma unroll
        for (int r = 0; r < 4; ++r) {
            const int i = strip + mt * 16 + q * 4 + r;
            u16x8 ev = *(const u16x8*)(Eb + (size_t)i * 128 + m * 8);
            #pragma unroll
            for (int nt = 0; nt < 8; ++nt) S[mt][nt][r] = bf2f(ev[nt]);
        }

    const bf16x8 zero8 = {};
    const int hf = q & 1;
    const size_t qko = (size_t)(plane * 2 + hf) * SP + jb;

    // Q A-frags (direct from global; q>=2 lanes = zero K-half)
    bf16x8 aQ[2];
    #pragma unroll
    for (int mt = 0; mt < 2; ++mt) {
        const size_t off = qko + (size_t)(strip + mt * 16 + m) * 8;
        aQ[mt] = (q < 2) ? *(const bf16x8*)(QT + off) : zero8;
    }

    // S tiles: B row for tile nt, lane m = K row k = m*8 + nt (permuted)
    #pragma unroll
    for (int nt = 0; nt < 8; ++nt) {
        const size_t koff = qko + (size_t)(m * 8 + nt) * 8;
        bf16x8 bK = (q < 2) ? *(const bf16x8*)(KT + koff) : zero8;
        #pragma unroll
        for (int mt = 0; mt < 2; ++mt)
            S[mt][nt] = MFMA16(aQ[mt], bK, S[mt][nt]);
    }

    // softmax (row cols spread over lanes m: xor 1,2,4,8) + gate + P -> LDS
    #pragma unroll
    for (int mt = 0; mt < 2; ++mt)
        #pragma unroll
        for (int r = 0; r < 4; ++r) {
            float v = -1e30f;
            #pragma unroll
            for (int nt = 0; nt < 8; ++nt) v = fmaxf(v, S[mt][nt][r]);
            v = fmaxf(v, __shfl_xor(v, 1)); v = fmaxf(v, __shfl_xor(v, 2));
            v = fmaxf(v, __shfl_xor(v, 4)); v = fmaxf(v, __shfl_xor(v, 8));
            float s = 0.f;
            #pragma unroll
            for (int nt = 0; nt < 8; ++nt) {
                float p = __expf(S[mt][nt][r] - v);
                S[mt][nt][r] = p;
                s += p;
            }
            s += __shfl_xor(s, 1); s += __shfl_xor(s, 2);
            s += __shfl_xor(s, 4); s += __shfl_xor(s, 8);
            const float inv = 1.f / s;
            const int i = strip + mt * 16 + q * 4 + r;
            u16x8 gv = *(const u16x8*)(Gb + (size_t)i * 128 + m * 8);
            #pragma unroll
            for (int nt = 0; nt < 4; ++nt) {
                Pl[i * 136 + nt * 16 + m] =
                    f2bf(S[mt][nt][r] * inv * bf2f(gv[nt]));
                Pl[i * 136 + (nt + 4) * 16 + m] =
                    f2bf(S[mt][nt + 4][r] * inv * bf2f(gv[nt + 4]));
            }
        }

    // ---- T14: deferred V write to LDS: Vth[d*136 + c] = V[k(c)][d] ----
    #pragma unroll
    for (int dd = 0; dd < 8; ++dd)
        Vth[(vch * 8 + dd) * 136 + vc] = vv[dd];

    __syncthreads();   // Vth/Pl ready

    // AV = P @ V (both in permuted-k order)
    f32x4 av[2] = {(f32x4){0.f, 0.f, 0.f, 0.f}, (f32x4){0.f, 0.f, 0.f, 0.f}};
    #pragma unroll
    for (int kc = 0; kc < 4; ++kc) {
        const int off = kc * 32 + q * 8;
        bf16x8 bV = *(const bf16x8*)&Vth[m * 136 + off];
        #pragma unroll
        for (int mt = 0; mt < 2; ++mt) {
            bf16x8 aP = *(const bf16x8*)&Pl[(strip + mt * 16 + m) * 136 + off];
            av[mt] = MFMA16(aP, bV, av[mt]);
        }
    }

    // store va' packed u32 (hi | lo<<16), row p' = j*128+i, col plane*16+d:
    // 8 dword stores/thread, 64B per 16 lanes.
    #pragma unroll
    for (int mt = 0; mt < 2; ++mt)
        #pragma unroll
        for (int r = 0; r < 4; ++r) {
            const int i = strip + mt * 16 + q * 4 + r;
            const size_t addr = ((size_t)(j * 128 + i)) * 256 + plane * 16 + m;
            const float x = av[mt][r];
            const unsigned short hi = f2bf(x);
            const unsigned short lo = f2bf(x - bf2f(hi));
            vaP[addr] = (unsigned int)hi | ((unsigned int)lo << 16);
        }
}

// ---------------- MFMA GEMM: output projection (va in p'/k' order) ----------
// grid(512), 256 thr. Tile 64(M) x 64(N). K=256; packed-u32 va unpacked with
// and/shift (bit-identical hi/lo). Row-permuted C store.
__global__ __launch_bounds__(256) void gemm_out_kernel(
    const unsigned int* __restrict__ vaP,
    const unsigned short* __restrict__ B3t,
    const float* __restrict__ bias,
    float* __restrict__ out)
{
    const int t = threadIdx.x;
    const int wave = t >> 6, lane = t & 63;
    const int m = lane & 15, q = lane >> 4;
    const int W0 = (blockIdx.x >> 1) * 64 + wave * 16;
    const int N0 = (blockIdx.x & 1) * 64;

    f32x4 acc[4];
    #pragma unroll
    for (int cc = 0; cc < 4; ++cc) acc[cc] = (f32x4){0.f, 0.f, 0.f, 0.f};

    const unsigned int* arow = vaP + (size_t)(W0 + m) * 256;
    const unsigned short* bcol[4];
    #pragma unroll
    for (int ns = 0; ns < 4; ++ns)
        bcol[ns] = B3t + (size_t)(N0 + ns * 16 + m) * 256;

    #pragma unroll 2
    for (int kc = 0; kc < 8; ++kc) {
        const int ko = kc * 32 + q * 8;
        u32x8 w = *(const u32x8*)(arow + ko);
        bf16x8 ah, al;
        #pragma unroll
        for (int jj = 0; jj < 8; ++jj) {
            ah[jj] = (short)(w[jj] & 0xffffu);
            al[jj] = (short)(w[jj] >> 16);
        }
        bf16x8 bh[4], bl[4];
        #pragma unroll
        for (int ns = 0; ns < 4; ++ns) {
            bh[ns] = *(const bf16x8*)(bcol[ns] + ko);
            bl[ns] = *(const bf16x8*)(bcol[ns] + 128 * 256 + ko);
        }
        #pragma unroll
        for (int ns = 0; ns < 4; ++ns) acc[ns] = MFMA16(ah, bh[ns], acc[ns]);
        #pragma unroll
        for (int ns = 0; ns < 4; ++ns) acc[ns] = MFMA16(al, bh[ns], acc[ns]);
        #pragma unroll
        for (int ns = 0; ns < 4; ++ns) acc[ns] = MFMA16(ah, bl[ns], acc[ns]);
    }

    #pragma unroll
    for (int ns = 0; ns < 4; ++ns) {
        const int col = N0 + ns * 16 + m;
        #pragma unroll
        for (int r = 0; r < 4; ++r) {
            const int prow = W0 + q * 4 + r;                 // p' = j*128+i
            const int orow = ((prow & 127) << 7) | (prow >> 7);  // i*128+j
            out[(size_t)orow * 128 + col] = acc[ns][r] + bias[col];
        }
    }
}

extern "C" void kernel_launch(void* const* d_in, const int* in_sizes, int n_in,
                              void* d_out, int out_size, void* d_ws, size_t ws_size,
                              hipStream_t stream) {
    const float* e        = (const float*)d_in[0];
    const float* mask     = (const float*)d_in[1];
    const float* ln_w     = (const float*)d_in[2];
    const float* ln_b     = (const float*)d_in[3];
    const float* w_qkv_in = (const float*)d_in[4];
    const float* b_qkv_in = (const float*)d_in[5];
    const float* w_eg_in  = (const float*)d_in[6];
    const float* b_eg_in  = (const float*)d_in[7];
    const float* w_qkv_o  = (const float*)d_in[8];
    const float* b_qkv_o  = (const float*)d_in[9];
    const float* w_eg_o   = (const float*)d_in[10];
    const float* b_eg_o   = (const float*)d_in[11];
    const float* w_o      = (const float*)d_in[12];
    const float* b_o      = (const float*)d_in[13];
    float* out = (float*)d_out;

    char* base = (char*)d_ws;
    const size_t PLANE = (size_t)16 * NPOS * 16;                      // ushorts per array
    unsigned short* e_hl = (unsigned short*)base;                     // 8.39 MB
    unsigned short* QT = (unsigned short*)(base + (size_t)NPOS * 256 * 2);
    unsigned short* KT = QT + PLANE;
    unsigned short* VT = KT + PLANE;
    unsigned int* vaP = (unsigned int*)(VT + PLANE);                  // 16.78 MB
    unsigned short* Etab = (unsigned short*)(vaP + (size_t)NPOS * 256);// 0.52 MB (bf16)
    unsigned short* Gtab = Etab + (size_t)16 * NPOS;                  // 0.52 MB
    unsigned short* B3t  = Gtab + (size_t)16 * NPOS;                  // 0.13 MB

    // aliases (lifetime-checked): B1t/B2t overlay vaP (dead before attn writes)
    unsigned short* B1t = (unsigned short*)vaP;
    unsigned short* B2t = B1t + (size_t)2 * 448 * 128;

    prep_kernel<<<4672, 256, 0, stream>>>(
        e, ln_w, ln_b, e_hl,
        w_qkv_in, w_eg_in, B1t, w_qkv_o, w_eg_o, B2t, w_o, B3t);

    gemm_qkv_kernel<<<dim3(128, 4, 2), 256, 0, stream>>>(
        e_hl, B1t, B2t, b_qkv_in, b_eg_in, b_qkv_o, b_eg_o, mask,
        QT, KT, VT, Etab, Gtab);

    attn_kernel<<<dim3(128, 8, 2), 256, 0, stream>>>(
        QT, KT, VT, Etab, Gtab, vaP);

    gemm_out_kernel<<<512, 256, 0, stream>>>(vaP, B3t, b_o, out);
}

// Round 8
// 157.281 us; speedup vs baseline: 3.7077x; 1.0201x over previous
//
#include <hip/hip_runtime.h>
#include <hip/hip_bf16.h>

// B=1, N=128, C=128, H=8, D=16. SCALE=0.25. All I/O fp32.
// GEMMs: bf16 MFMA, split-bf16 hi/lo 3-term for fp32 quality (e_hl, B-packs).
// Attention planes are HI-ONLY bf16. Plane arrays: [plane][dhalf][p][8] ushort.
// v14 = v13 + two changes:
//  - va HI-ONLY bf16 (8.4 MB): attn stores halve; gemm_out reads halve and
//    K-loop is 2-term (8 MFMA/kc). Drops the al*bh residual term: adds
//    ~6e-5..1.3e-4 error (threshold 3.44e-4 — margin ~2.5x).
//  - prep LN float4-vectorized (16B/lane), 2048 LN blocks of 8 rows.

#define NPOS 16384
#define CDIM 128

typedef __attribute__((ext_vector_type(8))) short bf16x8;
typedef __attribute__((ext_vector_type(8))) unsigned short u16x8;
typedef __attribute__((ext_vector_type(4))) float f32x4;

#define MFMA16(a, b, c) __builtin_amdgcn_mfma_f32_16x16x32_bf16((a), (b), (c), 0, 0, 0)

#define GLL16(gp, lp) __builtin_amdgcn_global_load_lds( \
    (const __attribute__((address_space(1))) void*)(gp), \
    (__attribute__((address_space(3))) void*)(lp), 16, 0, 0)

static __device__ __forceinline__ unsigned short f2bf(float x) {
    union { float f; unsigned int u; } v; v.f = x;
    unsigned int u = v.u;
    unsigned int r = u + 0x7FFFu + ((u >> 16) & 1u);   // RNE
    return (unsigned short)(r >> 16);
}
static __device__ __forceinline__ float bf2f(unsigned short h) {
    union { float f; unsigned int u; } v; v.u = ((unsigned int)h) << 16; return v.f;
}

// ---------------- prep: LayerNorm (float4) + all 3 weight packs -------------
// blocks 0..2047: ln (8 rows each, 32 lanes/row, float4); 2048..2495: pack
// B1t/B2t; 2496..2623: pack B3t (w_o, k' = (br*8+h)*16+d ordering).
__global__ __launch_bounds__(256) void prep_kernel(
    const float* __restrict__ e, const float* __restrict__ lnw,
    const float* __restrict__ lnb, unsigned short* __restrict__ e_hl,
    const float* __restrict__ wq1, const float* __restrict__ we1,
    unsigned short* __restrict__ B1t,
    const float* __restrict__ wq2, const float* __restrict__ we2,
    unsigned short* __restrict__ B2t,
    const float* __restrict__ wo, unsigned short* __restrict__ B3t)
{
    const int t = threadIdx.x;
    const int bx = blockIdx.x;
    if (bx < 2048) {
        const int row = bx * 8 + (t >> 5);
        const int lc = t & 31;                       // lane within row group
        float4 x = *(const float4*)(e + (size_t)row * CDIM + lc * 4);
        float s  = x.x + x.y + x.z + x.w;
        float s2 = x.x * x.x + x.y * x.y + x.z * x.z + x.w * x.w;
        #pragma unroll
        for (int off = 1; off < 32; off <<= 1) {     // stays within 32-group
            s  += __shfl_xor(s,  off, 64);
            s2 += __shfl_xor(s2, off, 64);
        }
        float m = s * (1.f / 128.f);
        float v = s2 * (1.f / 128.f) - m * m;
        float sc = rsqrtf(v + 1e-5f);
        float4 wv = *(const float4*)(lnw + lc * 4);
        float4 bv = *(const float4*)(lnb + lc * 4);
        float y[4] = {(x.x - m) * sc * wv.x + bv.x, (x.y - m) * sc * wv.y + bv.y,
                      (x.z - m) * sc * wv.z + bv.z, (x.w - m) * sc * wv.w + bv.w};
        ushort4 hi, lo;
        unsigned short h;
        h = f2bf(y[0]); hi.x = h; lo.x = f2bf(y[0] - bf2f(h));
        h = f2bf(y[1]); hi.y = h; lo.y = f2bf(y[1] - bf2f(h));
        h = f2bf(y[2]); hi.z = h; lo.z = f2bf(y[2] - bf2f(h));
        h = f2bf(y[3]); hi.w = h; lo.w = f2bf(y[3] - bf2f(h));
        *(ushort4*)(e_hl + (size_t)row * 256 + lc * 4)       = hi;
        *(ushort4*)(e_hl + (size_t)row * 256 + 128 + lc * 4) = lo;
    } else if (bx < 2496) {
        int pb = bx - 2048;
        const float* wq; const float* we; unsigned short* Bt;
        if (pb < 224) { wq = wq1; we = we1; Bt = B1t; }
        else          { pb -= 224; wq = wq2; we = we2; Bt = B2t; }
        const int idx = pb * 256 + t;    // n*128 + k
        const int n = idx >> 7, k = idx & 127;
        float v = 0.f;
        if (n < 384) v = wq[(size_t)k * 384 + n];
        else if (n < 400) v = we[(size_t)k * 16 + (n - 384)];
        unsigned short hi = f2bf(v);
        Bt[idx] = hi;
        Bt[448 * 128 + idx] = f2bf(v - bf2f(hi));
    } else {
        const int idx = (bx - 2496) * 256 + t;   // n*256 + kp
        const int n = idx >> 8, kp = idx & 255;
        const int d = kp & 15, pl = kp >> 4;
        const int k = d * 16 + pl;
        float v = wo[(size_t)k * 128 + n];
        unsigned short hi = f2bf(v);
        B3t[idx] = hi;
        B3t[128 * 256 + idx] = f2bf(v - bf2f(hi));
    }
}

// ---------------- MFMA GEMM: qkv+eg, global_load_lds staging, fused store --
// grid(128, 4, 2), 256 thr. by 0..2: tile 128(M) x 128(N) (Q, K, V); by 3:
// tile 128 x 64 (eg -> tables). K=128 in 4 chunks, single-buffered LDS.
// Subplanes consumed column-wise by attn (Q all br, K/V br=1) stored j-major;
// bx XCD-quad swizzled.
__global__ __launch_bounds__(256) void gemm_qkv_kernel(
    const unsigned short* __restrict__ e_hl,
    const unsigned short* __restrict__ B1t, const unsigned short* __restrict__ B2t,
    const float* __restrict__ bq_i, const float* __restrict__ be_i,
    const float* __restrict__ bq_o, const float* __restrict__ be_o,
    const float* __restrict__ mask,
    unsigned short* __restrict__ QT, unsigned short* __restrict__ KT,
    unsigned short* __restrict__ VT,
    unsigned short* __restrict__ Etab, unsigned short* __restrict__ Gtab)
{
    __shared__ __align__(16) unsigned char smem[33792];
    unsigned short* Alds = (unsigned short*)smem;            // [2][4][128][8] ushorts
    unsigned short* Blds = (unsigned short*)(smem + 16384);

    const int t = threadIdx.x;
    const int wave = t >> 6, lane = t & 63;
    const int m = lane & 15, q = lane >> 4;
    const int c = blockIdx.x;
    const int bx = ((c & 31) << 2) | (c >> 5);   // bx quads share an XCD
    const int W0blk = bx * 128;
    const int by = blockIdx.y;
    const int br = blockIdx.z;
    const unsigned short* Bt = br ? B2t : B1t;
    const float* bias_qkv = br ? bq_o : bq_i;
    const float* bias_eg  = br ? be_o : be_i;

    if (by < 3) {
        // ================= 128x128 Q/K/V tile =================
        const int N0 = by * 128;
        f32x4 acc[2][8];
        #pragma unroll
        for (int a = 0; a < 2; ++a)
            #pragma unroll
            for (int cc = 0; cc < 8; ++cc) acc[a][cc] = (f32x4){0.f, 0.f, 0.f, 0.f};

        for (int kc = 0; kc < 4; ++kc) {
            // stage A+B chunk: 32 wave-instrs, 8 per wave
            #pragma unroll
            for (int ii = 0; ii < 8; ++ii) {
                const int id = wave + ii * 4;        // 0..31, each once
                const int hl = (id >> 3) & 1;
                const int s = id & 7;
                const int qq = s >> 1, rbase = (s & 1) * 64;
                if (id < 16) {
                    const unsigned short* g = e_hl
                        + (size_t)(W0blk + rbase + lane) * 256 + hl * 128 + kc * 32 + qq * 8;
                    unsigned short* l = Alds + hl * 4096 + qq * 1024 + rbase * 8;
                    GLL16(g, l);
                } else {
                    const unsigned short* g = Bt + (size_t)(N0 + rbase + lane) * 128
                        + hl * (448 * 128) + kc * 32 + qq * 8;
                    unsigned short* l = Blds + hl * 4096 + qq * 1024 + rbase * 8;
                    GLL16(g, l);
                }
            }
            __syncthreads();   // drains vmcnt: staged data visible

            bf16x8 aH[2], aL[2];
            #pragma unroll
            for (int ms = 0; ms < 2; ++ms) {
                const int row = wave * 32 + ms * 16 + m;
                aH[ms] = *(const bf16x8*)(Alds + 0    + q * 1024 + row * 8);
                aL[ms] = *(const bf16x8*)(Alds + 4096 + q * 1024 + row * 8);
            }
            #pragma unroll
            for (int half = 0; half < 2; ++half) {
                bf16x8 bH[4], bL[4];
                #pragma unroll
                for (int ns = 0; ns < 4; ++ns) {
                    const int cc = (half * 4 + ns) * 16 + m;
                    bH[ns] = *(const bf16x8*)(Blds + 0    + q * 1024 + cc * 8);
                    bL[ns] = *(const bf16x8*)(Blds + 4096 + q * 1024 + cc * 8);
                }
                #pragma unroll
                for (int ns = 0; ns < 4; ++ns) {
                    const int nt = half * 4 + ns;
                    acc[0][nt] = MFMA16(aH[0], bH[ns], acc[0][nt]);
                    acc[1][nt] = MFMA16(aH[1], bH[ns], acc[1][nt]);
                }
                #pragma unroll
                for (int ns = 0; ns < 4; ++ns) {
                    const int nt = half * 4 + ns;
                    acc[0][nt] = MFMA16(aL[0], bH[ns], acc[0][nt]);
                    acc[1][nt] = MFMA16(aL[1], bH[ns], acc[1][nt]);
                }
                #pragma unroll
                for (int ns = 0; ns < 4; ++ns) {
                    const int nt = half * 4 + ns;
                    acc[0][nt] = MFMA16(aH[0], bL[ns], acc[0][nt]);
                    acc[1][nt] = MFMA16(aH[1], bL[ns], acc[1][nt]);
                }
            }
            __syncthreads();   // LDS reusable (next chunk / epilogue)
        }

        // epilogue: Ts16[128][130], both d-halves
        unsigned short (*Ts16)[130] = (unsigned short (*)[130])smem;
        #pragma unroll
        for (int ms = 0; ms < 2; ++ms)
            #pragma unroll
            for (int nt = 0; nt < 8; ++nt) {
                const int lc = nt * 16 + m;
                const int col = N0 + lc;
                const float bias = bias_qkv[col];
                const float scale = (col < 128) ? 0.25f : 1.f;
                #pragma unroll
                for (int r = 0; r < 4; ++r) {
                    const int lr = wave * 32 + ms * 16 + q * 4 + r;
                    Ts16[lr][lc] = f2bf((acc[ms][nt][r] + bias) * scale);
                }
            }
        __syncthreads();
        unsigned short* dstH = (by == 0) ? QT : (by == 1 ? KT : VT);
        // j-major (transposed) for the subplanes attn reads column-wise:
        const bool tr = (by == 0) || (br == 1);
        #pragma unroll
        for (int it = 0; it < 8; ++it) {
            int item = it * 256 + t;        // 0..2047: (hh, dhalf, lr)
            int hh = item >> 8;
            int dhalf = (item >> 7) & 1;
            int lr = item & 127;
            u16x8 hi;
            #pragma unroll
            for (int dd = 0; dd < 8; ++dd)
                hi[dd] = Ts16[lr][dhalf * 64 + dd * 8 + hh];
            const size_t sub = ((size_t)(br * 8 + hh) * 2 + dhalf) * NPOS;
            const size_t p16 = tr ? ((size_t)lr * 128 + bx)
                                  : ((size_t)bx * 128 + lr);
            *(u16x8*)(dstH + (sub + p16) * 8) = hi;
        }
    } else {
        // ================= 128x64 eg tile -> tables =================
        const int N0 = 384;
        f32x4 acc[2][4];
        #pragma unroll
        for (int a = 0; a < 2; ++a)
            #pragma unroll
            for (int cc = 0; cc < 4; ++cc) acc[a][cc] = (f32x4){0.f, 0.f, 0.f, 0.f};

        for (int kc = 0; kc < 4; ++kc) {
            #pragma unroll
            for (int ii = 0; ii < 6; ++ii) {
                const int id = wave + ii * 4;
                if (id < 16) {
                    const int hl = id >> 3, s = id & 7;
                    const int qq = s >> 1, rbase = (s & 1) * 64;
                    const unsigned short* g = e_hl
                        + (size_t)(W0blk + rbase + lane) * 256 + hl * 128 + kc * 32 + qq * 8;
                    unsigned short* l = Alds + hl * 4096 + qq * 1024 + rbase * 8;
                    GLL16(g, l);
                } else {
                    const int id2 = id - 16;
                    const int hl = id2 >> 2, qq = id2 & 3;
                    const unsigned short* g = Bt + (size_t)(N0 + lane) * 128
                        + hl * (448 * 128) + kc * 32 + qq * 8;
                    unsigned short* l = Blds + hl * 2048 + qq * 512;
                    GLL16(g, l);
                }
            }
            __syncthreads();

            bf16x8 aH[2], aL[2], bH[4], bL[4];
            #pragma unroll
            for (int ms = 0; ms < 2; ++ms) {
                const int row = wave * 32 + ms * 16 + m;
                aH[ms] = *(const bf16x8*)(Alds + 0    + q * 1024 + row * 8);
                aL[ms] = *(const bf16x8*)(Alds + 4096 + q * 1024 + row * 8);
            }
            #pragma unroll
            for (int ns = 0; ns < 4; ++ns) {
                bH[ns] = *(const bf16x8*)(Blds + 0    + q * 512 + (ns * 16 + m) * 8);
                bL[ns] = *(const bf16x8*)(Blds + 2048 + q * 512 + (ns * 16 + m) * 8);
            }
            #pragma unroll
            for (int ns = 0; ns < 4; ++ns) {
                acc[0][ns] = MFMA16(aH[0], bH[ns], acc[0][ns]);
                acc[1][ns] = MFMA16(aH[1], bH[ns], acc[1][ns]);
            }
            #pragma unroll
            for (int ns = 0; ns < 4; ++ns) {
                acc[0][ns] = MFMA16(aL[0], bH[ns], acc[0][ns]);
                acc[1][ns] = MFMA16(aL[1], bH[ns], acc[1][ns]);
            }
            #pragma unroll
            for (int ns = 0; ns < 4; ++ns) {
                acc[0][ns] = MFMA16(aH[0], bL[ns], acc[0][ns]);
                acc[1][ns] = MFMA16(aH[1], bL[ns], acc[1][ns]);
            }
            __syncthreads();
        }

        float* Tf = (float*)smem;   // [128][33], cols 0..15 used
        #pragma unroll
        for (int ms = 0; ms < 2; ++ms) {
            const float bias = bias_eg[m];
            #pragma unroll
            for (int r = 0; r < 4; ++r) {
                const int lr = wave * 32 + ms * 16 + q * 4 + r;
                Tf[lr * 33 + m] = acc[ms][0][r] + bias;
            }
        }
        __syncthreads();
        // Row p = bx*128 + r128. br=0: dst = p; br=1: dst = r128*128 + bx.
        const int r128 = t & 127, grp = t >> 7;
        const float mk = mask[bx * 128 + r128];
        const int dst = br ? (r128 * 128 + bx) : (bx * 128 + r128);
        if (grp == 0) {
            #pragma unroll
            for (int h = 0; h < 8; ++h)
                Etab[(size_t)(br * 8 + h) * NPOS + dst] =
                    f2bf(Tf[r128 * 33 + h] + mk);
        } else {
            #pragma unroll
            for (int h = 0; h < 8; ++h) {
                const float g = Tf[r128 * 33 + 8 + h] + mk;
                Gtab[(size_t)(br * 8 + h) * NPOS + dst] =
                    f2bf(1.f / (1.f + __expf(-g)));
            }
        }
    }
}

// ---------------- MFMA fused triangle attention (bf16 E/G, hi-only va) ------
// grid (j=128, h=8, br=2), 256 thr = 4 waves, wave owns 32-row strip.
// 4 blocks/CU (VGPR<=128 via launch_bounds, LDS 39.2KB). T14 V-stage split.
// S-column c maps to K-row k(c) = (c&15)*8 + (c>>4); softmax is k-permutation
// invariant and P/V use the same order, so the result is exact.
__global__ __launch_bounds__(256, 4) void attn_kernel(
    const unsigned short* __restrict__ QT, const unsigned short* __restrict__ KT,
    const unsigned short* __restrict__ VT,
    const unsigned short* __restrict__ Etab, const unsigned short* __restrict__ Gtab,
    unsigned short* __restrict__ vaH)
{
    const int j = blockIdx.x, h = blockIdx.y, br = blockIdx.z;
    const int t = threadIdx.x;
    const int wave = t >> 6, lane = t & 63;
    const int m = lane & 15, q = lane >> 4;
    const int plane = br * 8 + h;
    const size_t SP = (size_t)NPOS * 8;          // ushorts per sub-plane
    const size_t jb = (size_t)j * 128 * 8;
    const unsigned short* __restrict__ Eb = Etab + (size_t)plane * NPOS;
    const unsigned short* __restrict__ Gb = Gtab + (size_t)plane * NPOS;

    __shared__ unsigned short Vth[16 * 136];
    __shared__ unsigned short Pl[128 * 136];

    const int strip = wave * 32;

    // ---- T14: issue V global load FIRST (write to LDS deferred) ----
    const int vc = t >> 1, vch = t & 1;
    const int vkrow = (vc & 15) * 8 + (vc >> 4);
    const u16x8 vv = *(const u16x8*)(VT + (size_t)(plane * 2 + vch) * SP + jb
                                     + (size_t)vkrow * 8);

    // ---- E preload into the MFMA accumulator ----
    f32x4 S[2][8];
    #pragma unroll
    for (int mt = 0; mt < 2; ++mt)
        #pragma unroll
        for (int r = 0; r < 4; ++r) {
            const int i = strip + mt * 16 + q * 4 + r;
            u16x8 ev = *(const u16x8*)(Eb + (size_t)i * 128 + m * 8);
            #pragma unroll
            for (int nt = 0; nt < 8; ++nt) S[mt][nt][r] = bf2f(ev[nt]);
        }

    const bf16x8 zero8 = {};
    const int hf = q & 1;
    const size_t qko = (size_t)(plane * 2 + hf) * SP + jb;

    // Q A-frags (direct from global; q>=2 lanes = zero K-half)
    bf16x8 aQ[2];
    #pragma unroll
    for (int mt = 0; mt < 2; ++mt) {
        const size_t off = qko + (size_t)(strip + mt * 16 + m) * 8;
        aQ[mt] = (q < 2) ? *(const bf16x8*)(QT + off) : zero8;
    }

    // S tiles: B row for tile nt, lane m = K row k = m*8 + nt (permuted)
    #pragma unroll
    for (int nt = 0; nt < 8; ++nt) {
        const size_t koff = qko + (size_t)(m * 8 + nt) * 8;
        bf16x8 bK = (q < 2) ? *(const bf16x8*)(KT + koff) : zero8;
        #pragma unroll
        for (int mt = 0; mt < 2; ++mt)
            S[mt][nt] = MFMA16(aQ[mt], bK, S[mt][nt]);
    }

    // softmax (row cols spread over lanes m: xor 1,2,4,8) + gate + P -> LDS
    #pragma unroll
    for (int mt = 0; mt < 2; ++mt)
        #pragma unroll
        for (int r = 0; r < 4; ++r) {
            float v = -1e30f;
            #pragma unroll
            for (int nt = 0; nt < 8; ++nt) v = fmaxf(v, S[mt][nt][r]);
            v = fmaxf(v, __shfl_xor(v, 1)); v = fmaxf(v, __shfl_xor(v, 2));
            v = fmaxf(v, __shfl_xor(v, 4)); v = fmaxf(v, __shfl_xor(v, 8));
            float s = 0.f;
            #pragma unroll
            for (int nt = 0; nt < 8; ++nt) {
                float p = __expf(S[mt][nt][r] - v);
                S[mt][nt][r] = p;
                s += p;
            }
            s += __shfl_xor(s, 1); s += __shfl_xor(s, 2);
            s += __shfl_xor(s, 4); s += __shfl_xor(s, 8);
            const float inv = 1.f / s;
            const int i = strip + mt * 16 + q * 4 + r;
            u16x8 gv = *(const u16x8*)(Gb + (size_t)i * 128 + m * 8);
            #pragma unroll
            for (int nt = 0; nt < 4; ++nt) {
                Pl[i * 136 + nt * 16 + m] =
                    f2bf(S[mt][nt][r] * inv * bf2f(gv[nt]));
                Pl[i * 136 + (nt + 4) * 16 + m] =
                    f2bf(S[mt][nt + 4][r] * inv * bf2f(gv[nt + 4]));
            }
        }

    // ---- T14: deferred V write to LDS: Vth[d*136 + c] = V[k(c)][d] ----
    #pragma unroll
    for (int dd = 0; dd < 8; ++dd)
        Vth[(vch * 8 + dd) * 136 + vc] = vv[dd];

    __syncthreads();   // Vth/Pl ready

    // AV = P @ V (both in permuted-k order)
    f32x4 av[2] = {(f32x4){0.f, 0.f, 0.f, 0.f}, (f32x4){0.f, 0.f, 0.f, 0.f}};
    #pragma unroll
    for (int kc = 0; kc < 4; ++kc) {
        const int off = kc * 32 + q * 8;
        bf16x8 bV = *(const bf16x8*)&Vth[m * 136 + off];
        #pragma unroll
        for (int mt = 0; mt < 2; ++mt) {
            bf16x8 aP = *(const bf16x8*)&Pl[(strip + mt * 16 + m) * 136 + off];
            av[mt] = MFMA16(aP, bV, av[mt]);
        }
    }

    // store va' HI-ONLY bf16 (row p' = j*128+i, col k' = plane*16 + d):
    // 16 lanes x 2B contiguous = 32B segments.
    #pragma unroll
    for (int mt = 0; mt < 2; ++mt)
        #pragma unroll
        for (int r = 0; r < 4; ++r) {
            const int i = strip + mt * 16 + q * 4 + r;
            const size_t addr = ((size_t)(j * 128 + i)) * 256 + plane * 16 + m;
            vaH[addr] = f2bf(av[mt][r]);
        }
}

// ---------------- MFMA GEMM: output projection (va in p'/k' order) ----------
// grid(512), 256 thr. Tile 64(M) x 64(N). K=256; hi-only va, 2-term
// (ah*bh + ah*bl). Row-permuted C store.
__global__ __launch_bounds__(256) void gemm_out_kernel(
    const unsigned short* __restrict__ vaH,
    const unsigned short* __restrict__ B3t,
    const float* __restrict__ bias,
    float* __restrict__ out)
{
    const int t = threadIdx.x;
    const int wave = t >> 6, lane = t & 63;
    const int m = lane & 15, q = lane >> 4;
    const int W0 = (blockIdx.x >> 1) * 64 + wave * 16;
    const int N0 = (blockIdx.x & 1) * 64;

    f32x4 acc[4];
    #pragma unroll
    for (int cc = 0; cc < 4; ++cc) acc[cc] = (f32x4){0.f, 0.f, 0.f, 0.f};

    const unsigned short* arow = vaH + (size_t)(W0 + m) * 256;
    const unsigned short* bcol[4];
    #pragma unroll
    for (int ns = 0; ns < 4; ++ns)
        bcol[ns] = B3t + (size_t)(N0 + ns * 16 + m) * 256;

    #pragma unroll 2
    for (int kc = 0; kc < 8; ++kc) {
        const int ko = kc * 32 + q * 8;
        bf16x8 ah = *(const bf16x8*)(arow + ko);
        bf16x8 bh[4], bl[4];
        #pragma unroll
        for (int ns = 0; ns < 4; ++ns) {
            bh[ns] = *(const bf16x8*)(bcol[ns] + ko);
            bl[ns] = *(const bf16x8*)(bcol[ns] + 128 * 256 + ko);
        }
        #pragma unroll
        for (int ns = 0; ns < 4; ++ns) acc[ns] = MFMA16(ah, bh[ns], acc[ns]);
        #pragma unroll
        for (int ns = 0; ns < 4; ++ns) acc[ns] = MFMA16(ah, bl[ns], acc[ns]);
    }

    #pragma unroll
    for (int ns = 0; ns < 4; ++ns) {
        const int col = N0 + ns * 16 + m;
        #pragma unroll
        for (int r = 0; r < 4; ++r) {
            const int prow = W0 + q * 4 + r;                 // p' = j*128+i
            const int orow = ((prow & 127) << 7) | (prow >> 7);  // i*128+j
            out[(size_t)orow * 128 + col] = acc[ns][r] + bias[col];
        }
    }
}

extern "C" void kernel_launch(void* const* d_in, const int* in_sizes, int n_in,
                              void* d_out, int out_size, void* d_ws, size_t ws_size,
                              hipStream_t stream) {
    const float* e        = (const float*)d_in[0];
    const float* mask     = (const float*)d_in[1];
    const float* ln_w     = (const float*)d_in[2];
    const float* ln_b     = (const float*)d_in[3];
    const float* w_qkv_in = (const float*)d_in[4];
    const float* b_qkv_in = (const float*)d_in[5];
    const float* w_eg_in  = (const float*)d_in[6];
    const float* b_eg_in  = (const float*)d_in[7];
    const float* w_qkv_o  = (const float*)d_in[8];
    const float* b_qkv_o  = (const float*)d_in[9];
    const float* w_eg_o   = (const float*)d_in[10];
    const float* b_eg_o   = (const float*)d_in[11];
    const float* w_o      = (const float*)d_in[12];
    const float* b_o      = (const float*)d_in[13];
    float* out = (float*)d_out;

    char* base = (char*)d_ws;
    const size_t PLANE = (size_t)16 * NPOS * 16;                      // ushorts per array
    unsigned short* e_hl = (unsigned short*)base;                     // 8.39 MB
    unsigned short* QT = (unsigned short*)(base + (size_t)NPOS * 256 * 2);
    unsigned short* KT = QT + PLANE;
    unsigned short* VT = KT + PLANE;
    unsigned short* vaH = VT + PLANE;                                 // 8.39 MB
    unsigned short* Etab = vaH + (size_t)NPOS * 256;                  // 0.52 MB (bf16)
    unsigned short* Gtab = Etab + (size_t)16 * NPOS;                  // 0.52 MB
    unsigned short* B3t  = Gtab + (size_t)16 * NPOS;                  // 0.13 MB

    // aliases (lifetime-checked): B1t/B2t overlay vaH (dead before attn writes)
    unsigned short* B1t = vaH;
    unsigned short* B2t = B1t + (size_t)2 * 448 * 128;

    prep_kernel<<<2624, 256, 0, stream>>>(
        e, ln_w, ln_b, e_hl,
        w_qkv_in, w_eg_in, B1t, w_qkv_o, w_eg_o, B2t, w_o, B3t);

    gemm_qkv_kernel<<<dim3(128, 4, 2), 256, 0, stream>>>(
        e_hl, B1t, B2t, b_qkv_in, b_eg_in, b_qkv_o, b_eg_o, mask,
        QT, KT, VT, Etab, Gtab);

    attn_kernel<<<dim3(128, 8, 2), 256, 0, stream>>>(
        QT, KT, VT, Etab, Gtab, vaH);

    gemm_out_kernel<<<512, 256, 0, stream>>>(vaH, B3t, b_o, out);
}